// Round 5
// baseline (588.518 us; speedup 1.0000x reference)
//
#include <hip/hip_runtime.h>
#include <cstdint>
#include <cstddef>

// ---------------------------------------------------------------------------
// GEMM: C[M,128] = A[M,128] @ B[128,128], fp32, 128x128 block tile, BK=32,
// 8x8 per thread (VALU-bound ~100+ TF). A stored [k][row] in LDS -> b128 frags.
// ---------------------------------------------------------------------------
__global__ __launch_bounds__(256) void gemm128_f32(const float* __restrict__ A,
                                                   const float* __restrict__ B,
                                                   float* __restrict__ C, int M) {
  __shared__ float Ast[32][132];  // [k][row], +4 pad
  __shared__ float Bs[32][132];   // [k][col]
  const int t = threadIdx.x;      // 256 threads
  const int row0 = blockIdx.x * 128;
  const int ty = t >> 4, tx = t & 15;

  float acc[8][8] = {};

  for (int kt = 0; kt < 4; ++kt) {
    // Load A tile: 128 rows x 32 k (transpose into Ast[k][row])
#pragma unroll
    for (int i = 0; i < 4; ++i) {
      int idx = t + i * 256;           // 0..1023
      int r = idx >> 3;                // 0..127
      int kq = (idx & 7) * 4;          // 0,4,..,28
      float4 v = make_float4(0.f, 0.f, 0.f, 0.f);
      if (row0 + r < M)
        v = *reinterpret_cast<const float4*>(A + (size_t)(row0 + r) * 128 + kt * 32 + kq);
      Ast[kq + 0][r] = v.x;
      Ast[kq + 1][r] = v.y;
      Ast[kq + 2][r] = v.z;
      Ast[kq + 3][r] = v.w;
    }
    // Load B tile: 32 k x 128 cols
#pragma unroll
    for (int i = 0; i < 4; ++i) {
      int idx = t + i * 256;
      int k = idx >> 5;                // 0..31
      int c4 = (idx & 31) * 4;         // 0..124
      *reinterpret_cast<float4*>(&Bs[k][c4]) =
          *reinterpret_cast<const float4*>(B + (size_t)(kt * 32 + k) * 128 + c4);
    }
    __syncthreads();

#pragma unroll
    for (int k = 0; k < 32; ++k) {
      float4 a0 = *reinterpret_cast<float4*>(&Ast[k][ty * 8]);
      float4 a1 = *reinterpret_cast<float4*>(&Ast[k][ty * 8 + 4]);
      float4 b0 = *reinterpret_cast<float4*>(&Bs[k][tx * 8]);
      float4 b1 = *reinterpret_cast<float4*>(&Bs[k][tx * 8 + 4]);
      float a[8] = {a0.x, a0.y, a0.z, a0.w, a1.x, a1.y, a1.z, a1.w};
      float b[8] = {b0.x, b0.y, b0.z, b0.w, b1.x, b1.y, b1.z, b1.w};
#pragma unroll
      for (int i = 0; i < 8; ++i)
#pragma unroll
        for (int j = 0; j < 8; ++j) acc[i][j] += a[i] * b[j];
    }
    __syncthreads();
  }

#pragma unroll
  for (int i = 0; i < 8; ++i) {
    int r = row0 + ty * 8 + i;
    if (r < M) {
      float4 lo = make_float4(acc[i][0], acc[i][1], acc[i][2], acc[i][3]);
      float4 hi = make_float4(acc[i][4], acc[i][5], acc[i][6], acc[i][7]);
      *reinterpret_cast<float4*>(C + (size_t)r * 128 + tx * 8) = lo;
      *reinterpret_cast<float4*>(C + (size_t)r * 128 + tx * 8 + 4) = hi;
    }
  }
}

// ---------------------------------------------------------------------------
// CSR build: degree count -> single-block scan -> scatter (src + ep packed
// into ONE int2 per edge: halves write-allocate traffic vs two 4B stores).
// ---------------------------------------------------------------------------
__global__ void count_deg(const int* __restrict__ trg, int* __restrict__ deg, int E) {
  int e = blockIdx.x * blockDim.x + threadIdx.x;
  if (e < E) atomicAdd(&deg[trg[e]], 1);
}

__global__ void scan_offsets(const int* __restrict__ deg, int* __restrict__ row_off, int N) {
  __shared__ int sums[1024];
  const int t = threadIdx.x;
  const int per = (N + 1023) / 1024;
  const int beg = t * per;
  const int end = (beg + per < N) ? beg + per : N;
  int s = 0;
  for (int i = beg; i < end; ++i) s += deg[i];
  sums[t] = s;
  __syncthreads();
  for (int off = 1; off < 1024; off <<= 1) {
    int v = sums[t];
    int add = (t >= off) ? sums[t - off] : 0;
    __syncthreads();
    sums[t] = v + add;
    __syncthreads();
  }
  int excl = (t == 0) ? 0 : sums[t - 1];
  for (int i = beg; i < end; ++i) {
    row_off[i] = excl;
    excl += deg[i];
  }
  if (t == 1023) row_off[N] = sums[1023];
}

__global__ void scatter_csr(const int* __restrict__ src, const int* __restrict__ trg,
                            const float* __restrict__ ep, const int* __restrict__ row_off,
                            int* __restrict__ cursor, int2* __restrict__ edge2, int E) {
  int e = blockIdx.x * blockDim.x + threadIdx.x;
  if (e >= E) return;
  int n = trg[e];
  int pos = row_off[n] + atomicAdd(&cursor[n], 1);
  edge2[pos] = make_int2(src[e], __float_as_int(ep[e]));
}

// ---------------------------------------------------------------------------
// Per-node attention scores (unchanged)
// ---------------------------------------------------------------------------
template <int H, int F>
__global__ void node_scores(const float* __restrict__ proj, const float* __restrict__ a_src,
                            const float* __restrict__ a_trg, float* __restrict__ ssrc,
                            float* __restrict__ strg, int N) {
  int idx = blockIdx.x * blockDim.x + threadIdx.x;
  if (idx >= N * H) return;
  int n = idx / H, h = idx % H;
  const float* p = proj + (size_t)n * (H * F) + h * F;
  const float* as = a_src + h * F;
  const float* at = a_trg + h * F;
  float d1 = 0.f, d2 = 0.f;
#pragma unroll
  for (int f = 0; f < F; f += 4) {
    float4 pv = *reinterpret_cast<const float4*>(p + f);
    float4 av = *reinterpret_cast<const float4*>(as + f);
    float4 tv = *reinterpret_cast<const float4*>(at + f);
    d1 += pv.x * av.x + pv.y * av.y + pv.z * av.z + pv.w * av.w;
    d2 += pv.x * tv.x + pv.y * tv.y + pv.z * tv.z + pv.w * tv.w;
  }
  ssrc[idx] = d1;
  strg[idx] = d2;
}

// ---------------------------------------------------------------------------
// Fused aggregation: one wave per target node, single pass, inline scores.
//   - lanes 0-31 = half 0, 32-63 = half 1; each half owns all 128 features
//     (float4/lane, 512B coalesced proj row).
//   - 8 edges per iteration (4 per half) -> 8 independent gathers in flight.
// ---------------------------------------------------------------------------
template <int H, int F>
__global__ void aggregate(const int2* __restrict__ edge2, const int* __restrict__ row_off,
                          const float* __restrict__ ssrc, const float* __restrict__ strg,
                          const float* __restrict__ Wt, const float* __restrict__ a_tp,
                          const float* __restrict__ proj, const float* __restrict__ skip,
                          const float* __restrict__ bias, float* __restrict__ out, int N) {
  int wid = (blockIdx.x * blockDim.x + threadIdx.x) >> 6;
  if (wid >= N) return;
  const int lane = threadIdx.x & 63;
  const int half = lane >> 5;        // 0 or 1
  const int fl = (lane & 31) * 4;    // feature base (4 consecutive features)
  const int h = fl / F;              // this lane's head

  // c_h = <Wt[h,:], a_tp[h,:]> via xor-closed shfl reduce over the head's lanes
  float4 wt4 = *reinterpret_cast<const float4*>(Wt + fl);
  float4 at4 = *reinterpret_cast<const float4*>(a_tp + fl);
  float ch = wt4.x * at4.x + wt4.y * at4.y + wt4.z * at4.z + wt4.w * at4.w;
#pragma unroll
  for (int off = 1; off < (F / 4); off <<= 1) ch += __shfl_xor(ch, off);

  const float mt = strg[(size_t)wid * H + h];
  const int beg = row_off[wid];
  const int end = row_off[wid + 1];

  float ax = 0.f, ay = 0.f, az = 0.f, aw = 0.f;
  float denom = 0.f;

  for (int i = beg; i < end; i += 8) {
    int   s[4];
    float pe[4], e[4];
    float4 p[4];
#pragma unroll
    for (int q = 0; q < 4; ++q) {
      int ii = i + q * 2 + half;
      bool v = ii < end;
      int2 e2 = v ? edge2[ii] : make_int2(0, 0);
      s[q] = e2.x;
      pe[q] = __int_as_float(e2.y);
      e[q] = v ? 1.f : 0.f;  // validity; exp applied below
    }
#pragma unroll
    for (int q = 0; q < 4; ++q)
      p[q] = *reinterpret_cast<const float4*>(proj + (size_t)s[q] * (H * F) + fl);
#pragma unroll
    for (int q = 0; q < 4; ++q) {
      float sc = ssrc[(size_t)s[q] * H + h] + mt + pe[q] * ch;
      sc = sc > 0.f ? sc : 0.2f * sc;
      float ee = __expf(sc) * e[q];
      denom += ee;
      ax += p[q].x * ee;
      ay += p[q].y * ee;
      az += p[q].z * ee;
      aw += p[q].w * ee;
    }
  }

  denom += __shfl_xor(denom, 32);
  ax += __shfl_xor(ax, 32);
  ay += __shfl_xor(ay, 32);
  az += __shfl_xor(az, 32);
  aw += __shfl_xor(aw, 32);

  if (half == 0) {
    float inv = 1.0f / (denom + 1e-16f);
    size_t base = (size_t)wid * (H * F) + fl;
    float4 sk = *reinterpret_cast<const float4*>(skip + base);
    float4 bi = *reinterpret_cast<const float4*>(bias + fl);
    float o0 = ax * inv + sk.x + bi.x;
    float o1 = ay * inv + sk.y + bi.y;
    float o2 = az * inv + sk.z + bi.z;
    float o3 = aw * inv + sk.w + bi.w;
    o0 = o0 > 0.f ? o0 : __expf(o0) - 1.f;
    o1 = o1 > 0.f ? o1 : __expf(o1) - 1.f;
    o2 = o2 > 0.f ? o2 : __expf(o2) - 1.f;
    o3 = o3 > 0.f ? o3 : __expf(o3) - 1.f;
    float4 ov = make_float4(o0, o1, o2, o3);
    *reinterpret_cast<float4*>(out + base) = ov;
  }
}

// ---------------------------------------------------------------------------
extern "C" void kernel_launch(void* const* d_in, const int* in_sizes, int n_in,
                              void* d_out, int out_size, void* d_ws, size_t ws_size,
                              hipStream_t stream) {
  const float* x      = (const float*)d_in[0];
  const int*   ei     = (const int*)  d_in[1];
  const float* ep     = (const float*)d_in[2];
  const float* W1     = (const float*)d_in[3];
  const float* Wt1    = (const float*)d_in[4];
  const float* a_src1 = (const float*)d_in[5];
  const float* a_trg1 = (const float*)d_in[6];
  const float* a_tp1  = (const float*)d_in[7];
  const float* b1     = (const float*)d_in[8];
  const float* Wskip1 = (const float*)d_in[9];
  const float* W2     = (const float*)d_in[10];
  const float* Wt2    = (const float*)d_in[11];
  const float* a_src2 = (const float*)d_in[12];
  const float* a_trg2 = (const float*)d_in[13];
  const float* a_tp2  = (const float*)d_in[14];
  const float* b2     = (const float*)d_in[15];

  const int N = in_sizes[0] / 128;
  const int E = in_sizes[1] / 2;
  const int* srcA = ei;
  const int* trgA = ei + E;

  char* ws = (char*)d_ws;
  size_t off = 0;
  auto alloc = [&](size_t bytes) {
    void* p = ws + off;
    off += (bytes + 255) & ~(size_t)255;
    return p;
  };
  int*   degcur  = (int*)  alloc((size_t)2 * N * 4);  // deg | cursor (one memset)
  int*   deg     = degcur;
  int*   cursor  = degcur + N;
  int*   row_off = (int*)  alloc((size_t)(N + 1) * 4);
  int2*  edge2   = (int2*) alloc((size_t)E * 8);
  float* proj    = (float*)alloc((size_t)N * 128 * 4);
  float* skip1   = (float*)alloc((size_t)N * 128 * 4);
  float* hbuf    = (float*)alloc((size_t)N * 128 * 4);
  float* ssrc    = (float*)alloc((size_t)N * 8 * 4);
  float* strg    = (float*)alloc((size_t)N * 8 * 4);
  (void)ws_size; (void)n_in; (void)out_size;

  hipMemsetAsync(degcur, 0, (size_t)2 * N * 4, stream);

  const int eb = (E + 255) / 256;
  const int gb = (N + 127) / 128;

  // CSR build (shared by both layers)
  count_deg<<<eb, 256, 0, stream>>>(trgA, deg, E);
  scan_offsets<<<1, 1024, 0, stream>>>(deg, row_off, N);
  scatter_csr<<<eb, 256, 0, stream>>>(srcA, trgA, ep, row_off, cursor, edge2, E);

  // -------- Layer 1: H=8, F=16, concat, skip = x @ Wskip1 --------
  gemm128_f32<<<gb, 256, 0, stream>>>(x, W1, proj, N);
  gemm128_f32<<<gb, 256, 0, stream>>>(x, Wskip1, skip1, N);
  node_scores<8, 16><<<(N * 8 + 255) / 256, 256, 0, stream>>>(proj, a_src1, a_trg1, ssrc, strg, N);
  aggregate<8, 16><<<(N + 3) / 4, 256, 0, stream>>>(edge2, row_off, ssrc, strg, Wt1, a_tp1,
                                                    proj, skip1, b1, hbuf, N);

  // -------- Layer 2: H=1, F=128, mean (=identity), skip = identity --------
  gemm128_f32<<<gb, 256, 0, stream>>>(hbuf, W2, proj, N);
  node_scores<1, 128><<<(N + 255) / 256, 256, 0, stream>>>(proj, a_src2, a_trg2, ssrc, strg, N);
  aggregate<1, 128><<<(N + 3) / 4, 256, 0, stream>>>(edge2, row_off, ssrc, strg, Wt2, a_tp2,
                                                     proj, hbuf, b2, (float*)d_out, N);
}

// Round 6
// 502.012 us; speedup vs baseline: 1.1723x; 1.1723x over previous
//
#include <hip/hip_runtime.h>
#include <hip/hip_fp16.h>
#include <cstdint>
#include <cstddef>

// ---------------------------------------------------------------------------
// GEMM: C[M,128] = A[M,128] @ B[128,128], fp32, 64x128 block tile, BK=32,
// 4x8 per thread. 782 blocks -> ~3 resident/CU, barrier overlap across blocks.
// Optionally writes an fp16 copy (Ch) for the aggregate gather path.
// ---------------------------------------------------------------------------
__global__ __launch_bounds__(256) void gemm128_f32(const float* __restrict__ A,
                                                   const float* __restrict__ B,
                                                   float* __restrict__ C,
                                                   __half* __restrict__ Ch, int M) {
  __shared__ float Ast[32][68];   // [k][row], 64 rows +4 pad
  __shared__ float Bs[32][132];   // [k][col], 128 cols +4 pad
  const int t = threadIdx.x;      // 256 threads
  const int row0 = blockIdx.x * 64;
  const int ty = t >> 4, tx = t & 15;  // 16x16 thread grid

  float acc[4][8] = {};

  for (int kt = 0; kt < 4; ++kt) {
    // A tile: 64 rows x 32 k, transposed into Ast[k][row]; 512 float4, 2/thread
#pragma unroll
    for (int i = 0; i < 2; ++i) {
      int idx = t + i * 256;           // 0..511
      int r = idx >> 3;                // 0..63
      int kq = (idx & 7) * 4;          // 0,4,..,28
      float4 v = make_float4(0.f, 0.f, 0.f, 0.f);
      if (row0 + r < M)
        v = *reinterpret_cast<const float4*>(A + (size_t)(row0 + r) * 128 + kt * 32 + kq);
      Ast[kq + 0][r] = v.x;
      Ast[kq + 1][r] = v.y;
      Ast[kq + 2][r] = v.z;
      Ast[kq + 3][r] = v.w;
    }
    // B tile: 32 k x 128 cols; 1024 float4, 4/thread
#pragma unroll
    for (int i = 0; i < 4; ++i) {
      int idx = t + i * 256;
      int k = idx >> 5;                // 0..31
      int c4 = (idx & 31) * 4;         // 0..124
      *reinterpret_cast<float4*>(&Bs[k][c4]) =
          *reinterpret_cast<const float4*>(B + (size_t)(kt * 32 + k) * 128 + c4);
    }
    __syncthreads();

#pragma unroll
    for (int k = 0; k < 32; ++k) {
      float4 a4 = *reinterpret_cast<float4*>(&Ast[k][ty * 4]);
      float4 b0 = *reinterpret_cast<float4*>(&Bs[k][tx * 8]);
      float4 b1 = *reinterpret_cast<float4*>(&Bs[k][tx * 8 + 4]);
      float a[4] = {a4.x, a4.y, a4.z, a4.w};
      float b[8] = {b0.x, b0.y, b0.z, b0.w, b1.x, b1.y, b1.z, b1.w};
#pragma unroll
      for (int i = 0; i < 4; ++i)
#pragma unroll
        for (int j = 0; j < 8; ++j) acc[i][j] += a[i] * b[j];
    }
    __syncthreads();
  }

#pragma unroll
  for (int i = 0; i < 4; ++i) {
    int r = row0 + ty * 4 + i;
    if (r < M) {
      float4 lo = make_float4(acc[i][0], acc[i][1], acc[i][2], acc[i][3]);
      float4 hi = make_float4(acc[i][4], acc[i][5], acc[i][6], acc[i][7]);
      *reinterpret_cast<float4*>(C + (size_t)r * 128 + tx * 8) = lo;
      *reinterpret_cast<float4*>(C + (size_t)r * 128 + tx * 8 + 4) = hi;
      if (Ch) {
        __half2* hp = reinterpret_cast<__half2*>(Ch + (size_t)r * 128 + tx * 8);
        hp[0] = __floats2half2_rn(lo.x, lo.y);
        hp[1] = __floats2half2_rn(lo.z, lo.w);
        hp[2] = __floats2half2_rn(hi.x, hi.y);
        hp[3] = __floats2half2_rn(hi.z, hi.w);
      }
    }
  }
}

// ---------------------------------------------------------------------------
// CSR build (unchanged from R5)
// ---------------------------------------------------------------------------
__global__ void count_deg(const int* __restrict__ trg, int* __restrict__ deg, int E) {
  int e = blockIdx.x * blockDim.x + threadIdx.x;
  if (e < E) atomicAdd(&deg[trg[e]], 1);
}

__global__ void scan_offsets(const int* __restrict__ deg, int* __restrict__ row_off, int N) {
  __shared__ int sums[1024];
  const int t = threadIdx.x;
  const int per = (N + 1023) / 1024;
  const int beg = t * per;
  const int end = (beg + per < N) ? beg + per : N;
  int s = 0;
  for (int i = beg; i < end; ++i) s += deg[i];
  sums[t] = s;
  __syncthreads();
  for (int off = 1; off < 1024; off <<= 1) {
    int v = sums[t];
    int add = (t >= off) ? sums[t - off] : 0;
    __syncthreads();
    sums[t] = v + add;
    __syncthreads();
  }
  int excl = (t == 0) ? 0 : sums[t - 1];
  for (int i = beg; i < end; ++i) {
    row_off[i] = excl;
    excl += deg[i];
  }
  if (t == 1023) row_off[N] = sums[1023];
}

__global__ void scatter_csr(const int* __restrict__ src, const int* __restrict__ trg,
                            const float* __restrict__ ep, const int* __restrict__ row_off,
                            int* __restrict__ cursor, int2* __restrict__ edge2, int E) {
  int e = blockIdx.x * blockDim.x + threadIdx.x;
  if (e >= E) return;
  int n = trg[e];
  int pos = row_off[n] + atomicAdd(&cursor[n], 1);
  edge2[pos] = make_int2(src[e], __float_as_int(ep[e]));
}

// ---------------------------------------------------------------------------
// Per-node attention scores (unchanged; reads fp32 proj)
// ---------------------------------------------------------------------------
template <int H, int F>
__global__ void node_scores(const float* __restrict__ proj, const float* __restrict__ a_src,
                            const float* __restrict__ a_trg, float* __restrict__ ssrc,
                            float* __restrict__ strg, int N) {
  int idx = blockIdx.x * blockDim.x + threadIdx.x;
  if (idx >= N * H) return;
  int n = idx / H, h = idx % H;
  const float* p = proj + (size_t)n * (H * F) + h * F;
  const float* as = a_src + h * F;
  const float* at = a_trg + h * F;
  float d1 = 0.f, d2 = 0.f;
#pragma unroll
  for (int f = 0; f < F; f += 4) {
    float4 pv = *reinterpret_cast<const float4*>(p + f);
    float4 av = *reinterpret_cast<const float4*>(as + f);
    float4 tv = *reinterpret_cast<const float4*>(at + f);
    d1 += pv.x * av.x + pv.y * av.y + pv.z * av.z + pv.w * av.w;
    d2 += pv.x * tv.x + pv.y * tv.y + pv.z * tv.z + pv.w * tv.w;
  }
  ssrc[idx] = d1;
  strg[idx] = d2;
}

// ---------------------------------------------------------------------------
// Fused aggregation: one wave per target node, single pass, inline scores.
// proj gathered as fp16 (256B/row: halves the dominant gather traffic).
// ---------------------------------------------------------------------------
template <int H, int F>
__global__ void aggregate(const int2* __restrict__ edge2, const int* __restrict__ row_off,
                          const float* __restrict__ ssrc, const float* __restrict__ strg,
                          const float* __restrict__ Wt, const float* __restrict__ a_tp,
                          const __half* __restrict__ projh, const float* __restrict__ skip,
                          const float* __restrict__ bias, float* __restrict__ out, int N) {
  int wid = (blockIdx.x * blockDim.x + threadIdx.x) >> 6;
  if (wid >= N) return;
  const int lane = threadIdx.x & 63;
  const int half = lane >> 5;        // 0 or 1
  const int fl = (lane & 31) * 4;    // feature base (4 consecutive features)
  const int h = fl / F;              // this lane's head

  // c_h = <Wt[h,:], a_tp[h,:]> via xor-closed shfl reduce over the head's lanes
  float4 wt4 = *reinterpret_cast<const float4*>(Wt + fl);
  float4 at4 = *reinterpret_cast<const float4*>(a_tp + fl);
  float ch = wt4.x * at4.x + wt4.y * at4.y + wt4.z * at4.z + wt4.w * at4.w;
#pragma unroll
  for (int off = 1; off < (F / 4); off <<= 1) ch += __shfl_xor(ch, off);

  const float mt = strg[(size_t)wid * H + h];
  const int beg = row_off[wid];
  const int end = row_off[wid + 1];

  float ax = 0.f, ay = 0.f, az = 0.f, aw = 0.f;
  float denom = 0.f;

  for (int i = beg; i < end; i += 8) {
    int   s[4];
    float pe[4], vd[4];
    float2 raw[4];
#pragma unroll
    for (int q = 0; q < 4; ++q) {
      int ii = i + q * 2 + half;
      bool v = ii < end;
      int2 e2 = v ? edge2[ii] : make_int2(0, 0);
      s[q] = e2.x;
      pe[q] = __int_as_float(e2.y);
      vd[q] = v ? 1.f : 0.f;
    }
#pragma unroll
    for (int q = 0; q < 4; ++q)
      raw[q] = *reinterpret_cast<const float2*>(projh + (size_t)s[q] * (H * F) + fl);
#pragma unroll
    for (int q = 0; q < 4; ++q) {
      float sc = ssrc[(size_t)s[q] * H + h] + mt + pe[q] * ch;
      sc = sc > 0.f ? sc : 0.2f * sc;
      float ee = __expf(sc) * vd[q];
      __half2 h01 = *reinterpret_cast<__half2*>(&raw[q].x);
      __half2 h23 = *reinterpret_cast<__half2*>(&raw[q].y);
      float2 f01 = __half22float2(h01);
      float2 f23 = __half22float2(h23);
      denom += ee;
      ax += f01.x * ee;
      ay += f01.y * ee;
      az += f23.x * ee;
      aw += f23.y * ee;
    }
  }

  denom += __shfl_xor(denom, 32);
  ax += __shfl_xor(ax, 32);
  ay += __shfl_xor(ay, 32);
  az += __shfl_xor(az, 32);
  aw += __shfl_xor(aw, 32);

  if (half == 0) {
    float inv = 1.0f / (denom + 1e-16f);
    size_t base = (size_t)wid * (H * F) + fl;
    float4 sk = *reinterpret_cast<const float4*>(skip + base);
    float4 bi = *reinterpret_cast<const float4*>(bias + fl);
    float o0 = ax * inv + sk.x + bi.x;
    float o1 = ay * inv + sk.y + bi.y;
    float o2 = az * inv + sk.z + bi.z;
    float o3 = aw * inv + sk.w + bi.w;
    o0 = o0 > 0.f ? o0 : __expf(o0) - 1.f;
    o1 = o1 > 0.f ? o1 : __expf(o1) - 1.f;
    o2 = o2 > 0.f ? o2 : __expf(o2) - 1.f;
    o3 = o3 > 0.f ? o3 : __expf(o3) - 1.f;
    float4 ov = make_float4(o0, o1, o2, o3);
    *reinterpret_cast<float4*>(out + base) = ov;
  }
}

// ---------------------------------------------------------------------------
extern "C" void kernel_launch(void* const* d_in, const int* in_sizes, int n_in,
                              void* d_out, int out_size, void* d_ws, size_t ws_size,
                              hipStream_t stream) {
  const float* x      = (const float*)d_in[0];
  const int*   ei     = (const int*)  d_in[1];
  const float* ep     = (const float*)d_in[2];
  const float* W1     = (const float*)d_in[3];
  const float* Wt1    = (const float*)d_in[4];
  const float* a_src1 = (const float*)d_in[5];
  const float* a_trg1 = (const float*)d_in[6];
  const float* a_tp1  = (const float*)d_in[7];
  const float* b1     = (const float*)d_in[8];
  const float* Wskip1 = (const float*)d_in[9];
  const float* W2     = (const float*)d_in[10];
  const float* Wt2    = (const float*)d_in[11];
  const float* a_src2 = (const float*)d_in[12];
  const float* a_trg2 = (const float*)d_in[13];
  const float* a_tp2  = (const float*)d_in[14];
  const float* b2     = (const float*)d_in[15];

  const int N = in_sizes[0] / 128;
  const int E = in_sizes[1] / 2;
  const int* srcA = ei;
  const int* trgA = ei + E;

  char* ws = (char*)d_ws;
  size_t off = 0;
  auto alloc = [&](size_t bytes) {
    void* p = ws + off;
    off += (bytes + 255) & ~(size_t)255;
    return p;
  };
  int*    degcur  = (int*)   alloc((size_t)2 * N * 4);  // deg | cursor (one memset)
  int*    deg     = degcur;
  int*    cursor  = degcur + N;
  int*    row_off = (int*)   alloc((size_t)(N + 1) * 4);
  int2*   edge2   = (int2*)  alloc((size_t)E * 8);
  float*  proj    = (float*) alloc((size_t)N * 128 * 4);
  __half* projh   = (__half*)alloc((size_t)N * 128 * 2);
  float*  skip1   = (float*) alloc((size_t)N * 128 * 4);
  float*  hbuf    = (float*) alloc((size_t)N * 128 * 4);
  float*  ssrc    = (float*) alloc((size_t)N * 8 * 4);
  float*  strg    = (float*) alloc((size_t)N * 8 * 4);
  (void)ws_size; (void)n_in; (void)out_size;

  hipMemsetAsync(degcur, 0, (size_t)2 * N * 4, stream);

  const int eb = (E + 255) / 256;
  const int gb = (N + 63) / 64;

  // CSR build (shared by both layers)
  count_deg<<<eb, 256, 0, stream>>>(trgA, deg, E);
  scan_offsets<<<1, 1024, 0, stream>>>(deg, row_off, N);
  scatter_csr<<<eb, 256, 0, stream>>>(srcA, trgA, ep, row_off, cursor, edge2, E);

  // -------- Layer 1: H=8, F=16, concat, skip = x @ Wskip1 --------
  gemm128_f32<<<gb, 256, 0, stream>>>(x, W1, proj, projh, N);
  gemm128_f32<<<gb, 256, 0, stream>>>(x, Wskip1, skip1, (__half*)nullptr, N);
  node_scores<8, 16><<<(N * 8 + 255) / 256, 256, 0, stream>>>(proj, a_src1, a_trg1, ssrc, strg, N);
  aggregate<8, 16><<<(N + 3) / 4, 256, 0, stream>>>(edge2, row_off, ssrc, strg, Wt1, a_tp1,
                                                    projh, skip1, b1, hbuf, N);

  // -------- Layer 2: H=1, F=128, mean (=identity), skip = identity --------
  gemm128_f32<<<gb, 256, 0, stream>>>(hbuf, W2, proj, projh, N);
  node_scores<1, 128><<<(N + 255) / 256, 256, 0, stream>>>(proj, a_src2, a_trg2, ssrc, strg, N);
  aggregate<1, 128><<<(N + 3) / 4, 256, 0, stream>>>(edge2, row_off, ssrc, strg, Wt2, a_tp2,
                                                     projh, hbuf, b2, (float*)d_out, N);
}

// Round 7
// 434.687 us; speedup vs baseline: 1.3539x; 1.1549x over previous
//
#include <hip/hip_runtime.h>
#include <hip/hip_fp16.h>
#include <cstdint>
#include <cstddef>

// ---------------------------------------------------------------------------
// GEMM: C[M,128] = A[M,128] @ B[128,128], fp32, 64x128 block tile, BK=32,
// 4x8 per thread. Optionally writes an fp16 copy (Ch) for the gather path.
// ---------------------------------------------------------------------------
__global__ __launch_bounds__(256) void gemm128_f32(const float* __restrict__ A,
                                                   const float* __restrict__ B,
                                                   float* __restrict__ C,
                                                   __half* __restrict__ Ch, int M) {
  __shared__ float Ast[32][68];   // [k][row], 64 rows +4 pad
  __shared__ float Bs[32][132];   // [k][col], 128 cols +4 pad
  const int t = threadIdx.x;      // 256 threads
  const int row0 = blockIdx.x * 64;
  const int ty = t >> 4, tx = t & 15;  // 16x16 thread grid

  float acc[4][8] = {};

  for (int kt = 0; kt < 4; ++kt) {
#pragma unroll
    for (int i = 0; i < 2; ++i) {
      int idx = t + i * 256;           // 0..511
      int r = idx >> 3;                // 0..63
      int kq = (idx & 7) * 4;          // 0,4,..,28
      float4 v = make_float4(0.f, 0.f, 0.f, 0.f);
      if (row0 + r < M)
        v = *reinterpret_cast<const float4*>(A + (size_t)(row0 + r) * 128 + kt * 32 + kq);
      Ast[kq + 0][r] = v.x;
      Ast[kq + 1][r] = v.y;
      Ast[kq + 2][r] = v.z;
      Ast[kq + 3][r] = v.w;
    }
#pragma unroll
    for (int i = 0; i < 4; ++i) {
      int idx = t + i * 256;
      int k = idx >> 5;                // 0..31
      int c4 = (idx & 31) * 4;         // 0..124
      *reinterpret_cast<float4*>(&Bs[k][c4]) =
          *reinterpret_cast<const float4*>(B + (size_t)(kt * 32 + k) * 128 + c4);
    }
    __syncthreads();

#pragma unroll
    for (int k = 0; k < 32; ++k) {
      float4 a4 = *reinterpret_cast<float4*>(&Ast[k][ty * 4]);
      float4 b0 = *reinterpret_cast<float4*>(&Bs[k][tx * 8]);
      float4 b1 = *reinterpret_cast<float4*>(&Bs[k][tx * 8 + 4]);
      float a[4] = {a4.x, a4.y, a4.z, a4.w};
      float b[8] = {b0.x, b0.y, b0.z, b0.w, b1.x, b1.y, b1.z, b1.w};
#pragma unroll
      for (int i = 0; i < 4; ++i)
#pragma unroll
        for (int j = 0; j < 8; ++j) acc[i][j] += a[i] * b[j];
    }
    __syncthreads();
  }

#pragma unroll
  for (int i = 0; i < 4; ++i) {
    int r = row0 + ty * 4 + i;
    if (r < M) {
      float4 lo = make_float4(acc[i][0], acc[i][1], acc[i][2], acc[i][3]);
      float4 hi = make_float4(acc[i][4], acc[i][5], acc[i][6], acc[i][7]);
      *reinterpret_cast<float4*>(C + (size_t)r * 128 + tx * 8) = lo;
      *reinterpret_cast<float4*>(C + (size_t)r * 128 + tx * 8 + 4) = hi;
      if (Ch) {
        __half2* hp = reinterpret_cast<__half2*>(Ch + (size_t)r * 128 + tx * 8);
        hp[0] = __floats2half2_rn(lo.x, lo.y);
        hp[1] = __floats2half2_rn(lo.z, lo.w);
        hp[2] = __floats2half2_rn(hi.x, hi.y);
        hp[3] = __floats2half2_rn(hi.z, hi.w);
      }
    }
  }
}

// ---------------------------------------------------------------------------
// CSR build: count -> 3-kernel hierarchical scan (full-width) -> int2 scatter
// ---------------------------------------------------------------------------
__global__ void count_deg(const int* __restrict__ trg, int* __restrict__ deg, int E) {
  int e = blockIdx.x * blockDim.x + threadIdx.x;
  if (e < E) atomicAdd(&deg[trg[e]], 1);
}

// pass 1: per-block (256-chunk) sums
__global__ void scan_bsum(const int* __restrict__ deg, int* __restrict__ bsum, int N) {
  __shared__ int ws[4];
  int i = blockIdx.x * 256 + threadIdx.x;
  int v = (i < N) ? deg[i] : 0;
#pragma unroll
  for (int off = 1; off < 64; off <<= 1) v += __shfl_xor(v, off);
  if ((threadIdx.x & 63) == 0) ws[threadIdx.x >> 6] = v;
  __syncthreads();
  if (threadIdx.x == 0) bsum[blockIdx.x] = ws[0] + ws[1] + ws[2] + ws[3];
}

// pass 2: exclusive scan of block sums (nb <= 256), one small block;
// also writes row_off[N] = total.
__global__ void scan_top(const int* __restrict__ bsum, int* __restrict__ boff,
                         int* __restrict__ row_off, int nb, int N) {
  __shared__ int s[256];
  int t = threadIdx.x;
  int v = (t < nb) ? bsum[t] : 0;
  s[t] = v;
  __syncthreads();
#pragma unroll
  for (int off = 1; off < 256; off <<= 1) {
    int x = s[t];
    int add = (t >= off) ? s[t - off] : 0;
    __syncthreads();
    s[t] = x + add;
    __syncthreads();
  }
  if (t < nb) boff[t] = (t == 0) ? 0 : s[t - 1];
  if (t == 0) row_off[N] = s[255];
}

// pass 3: block-local exclusive scan + block base -> row_off
__global__ void scan_local(const int* __restrict__ deg, const int* __restrict__ boff,
                           int* __restrict__ row_off, int N) {
  __shared__ int s[256];
  int t = threadIdx.x;
  int i = blockIdx.x * 256 + t;
  int v = (i < N) ? deg[i] : 0;
  s[t] = v;
  __syncthreads();
#pragma unroll
  for (int off = 1; off < 256; off <<= 1) {
    int x = s[t];
    int add = (t >= off) ? s[t - off] : 0;
    __syncthreads();
    s[t] = x + add;
    __syncthreads();
  }
  if (i < N) row_off[i] = boff[blockIdx.x] + (t == 0 ? 0 : s[t - 1]);
}

__global__ void scatter_csr(const int* __restrict__ src, const int* __restrict__ trg,
                            const float* __restrict__ ep, const int* __restrict__ row_off,
                            int* __restrict__ cursor, int2* __restrict__ edge2, int E) {
  int e = blockIdx.x * blockDim.x + threadIdx.x;
  if (e >= E) return;
  int n = trg[e];
  int pos = row_off[n] + atomicAdd(&cursor[n], 1);
  edge2[pos] = make_int2(src[e], __float_as_int(ep[e]));
}

// ---------------------------------------------------------------------------
// Per-node attention scores (unchanged; reads fp32 proj)
// ---------------------------------------------------------------------------
template <int H, int F>
__global__ void node_scores(const float* __restrict__ proj, const float* __restrict__ a_src,
                            const float* __restrict__ a_trg, float* __restrict__ ssrc,
                            float* __restrict__ strg, int N) {
  int idx = blockIdx.x * blockDim.x + threadIdx.x;
  if (idx >= N * H) return;
  int n = idx / H, h = idx % H;
  const float* p = proj + (size_t)n * (H * F) + h * F;
  const float* as = a_src + h * F;
  const float* at = a_trg + h * F;
  float d1 = 0.f, d2 = 0.f;
#pragma unroll
  for (int f = 0; f < F; f += 4) {
    float4 pv = *reinterpret_cast<const float4*>(p + f);
    float4 av = *reinterpret_cast<const float4*>(as + f);
    float4 tv = *reinterpret_cast<const float4*>(at + f);
    d1 += pv.x * av.x + pv.y * av.y + pv.z * av.z + pv.w * av.w;
    d2 += pv.x * tv.x + pv.y * tv.y + pv.z * tv.z + pv.w * tv.w;
  }
  ssrc[idx] = d1;
  strg[idx] = d2;
}

// ---------------------------------------------------------------------------
// Fused aggregation: one wave per target node, single pass, inline scores,
// fp16 proj gather (256B/row).
// ---------------------------------------------------------------------------
template <int H, int F>
__global__ void aggregate(const int2* __restrict__ edge2, const int* __restrict__ row_off,
                          const float* __restrict__ ssrc, const float* __restrict__ strg,
                          const float* __restrict__ Wt, const float* __restrict__ a_tp,
                          const __half* __restrict__ projh, const float* __restrict__ skip,
                          const float* __restrict__ bias, float* __restrict__ out, int N) {
  int wid = (blockIdx.x * blockDim.x + threadIdx.x) >> 6;
  if (wid >= N) return;
  const int lane = threadIdx.x & 63;
  const int half = lane >> 5;        // 0 or 1
  const int fl = (lane & 31) * 4;    // feature base (4 consecutive features)
  const int h = fl / F;              // this lane's head

  float4 wt4 = *reinterpret_cast<const float4*>(Wt + fl);
  float4 at4 = *reinterpret_cast<const float4*>(a_tp + fl);
  float ch = wt4.x * at4.x + wt4.y * at4.y + wt4.z * at4.z + wt4.w * at4.w;
#pragma unroll
  for (int off = 1; off < (F / 4); off <<= 1) ch += __shfl_xor(ch, off);

  const float mt = strg[(size_t)wid * H + h];
  const int beg = row_off[wid];
  const int end = row_off[wid + 1];

  float ax = 0.f, ay = 0.f, az = 0.f, aw = 0.f;
  float denom = 0.f;

  for (int i = beg; i < end; i += 8) {
    int   s[4];
    float pe[4], vd[4];
    float2 raw[4];
#pragma unroll
    for (int q = 0; q < 4; ++q) {
      int ii = i + q * 2 + half;
      bool v = ii < end;
      int2 e2 = v ? edge2[ii] : make_int2(0, 0);
      s[q] = e2.x;
      pe[q] = __int_as_float(e2.y);
      vd[q] = v ? 1.f : 0.f;
    }
#pragma unroll
    for (int q = 0; q < 4; ++q)
      raw[q] = *reinterpret_cast<const float2*>(projh + (size_t)s[q] * (H * F) + fl);
#pragma unroll
    for (int q = 0; q < 4; ++q) {
      float sc = ssrc[(size_t)s[q] * H + h] + mt + pe[q] * ch;
      sc = sc > 0.f ? sc : 0.2f * sc;
      float ee = __expf(sc) * vd[q];
      __half2 h01 = *reinterpret_cast<__half2*>(&raw[q].x);
      __half2 h23 = *reinterpret_cast<__half2*>(&raw[q].y);
      float2 f01 = __half22float2(h01);
      float2 f23 = __half22float2(h23);
      denom += ee;
      ax += f01.x * ee;
      ay += f01.y * ee;
      az += f23.x * ee;
      aw += f23.y * ee;
    }
  }

  denom += __shfl_xor(denom, 32);
  ax += __shfl_xor(ax, 32);
  ay += __shfl_xor(ay, 32);
  az += __shfl_xor(az, 32);
  aw += __shfl_xor(aw, 32);

  if (half == 0) {
    float inv = 1.0f / (denom + 1e-16f);
    size_t base = (size_t)wid * (H * F) + fl;
    float4 sk = *reinterpret_cast<const float4*>(skip + base);
    float4 bi = *reinterpret_cast<const float4*>(bias + fl);
    float o0 = ax * inv + sk.x + bi.x;
    float o1 = ay * inv + sk.y + bi.y;
    float o2 = az * inv + sk.z + bi.z;
    float o3 = aw * inv + sk.w + bi.w;
    o0 = o0 > 0.f ? o0 : __expf(o0) - 1.f;
    o1 = o1 > 0.f ? o1 : __expf(o1) - 1.f;
    o2 = o2 > 0.f ? o2 : __expf(o2) - 1.f;
    o3 = o3 > 0.f ? o3 : __expf(o3) - 1.f;
    float4 ov = make_float4(o0, o1, o2, o3);
    *reinterpret_cast<float4*>(out + base) = ov;
  }
}

// ---------------------------------------------------------------------------
extern "C" void kernel_launch(void* const* d_in, const int* in_sizes, int n_in,
                              void* d_out, int out_size, void* d_ws, size_t ws_size,
                              hipStream_t stream) {
  const float* x      = (const float*)d_in[0];
  const int*   ei     = (const int*)  d_in[1];
  const float* ep     = (const float*)d_in[2];
  const float* W1     = (const float*)d_in[3];
  const float* Wt1    = (const float*)d_in[4];
  const float* a_src1 = (const float*)d_in[5];
  const float* a_trg1 = (const float*)d_in[6];
  const float* a_tp1  = (const float*)d_in[7];
  const float* b1     = (const float*)d_in[8];
  const float* Wskip1 = (const float*)d_in[9];
  const float* W2     = (const float*)d_in[10];
  const float* Wt2    = (const float*)d_in[11];
  const float* a_src2 = (const float*)d_in[12];
  const float* a_trg2 = (const float*)d_in[13];
  const float* a_tp2  = (const float*)d_in[14];
  const float* b2     = (const float*)d_in[15];

  const int N = in_sizes[0] / 128;
  const int E = in_sizes[1] / 2;
  const int* srcA = ei;
  const int* trgA = ei + E;

  char* ws = (char*)d_ws;
  size_t off = 0;
  auto alloc = [&](size_t bytes) {
    void* p = ws + off;
    off += (bytes + 255) & ~(size_t)255;
    return p;
  };
  int*    degcur  = (int*)   alloc((size_t)2 * N * 4);  // deg | cursor (one memset)
  int*    deg     = degcur;
  int*    cursor  = degcur + N;
  int*    row_off = (int*)   alloc((size_t)(N + 1) * 4);
  int*    bsum    = (int*)   alloc((size_t)256 * 4);
  int*    boff    = (int*)   alloc((size_t)256 * 4);
  int2*   edge2   = (int2*)  alloc((size_t)E * 8);
  float*  proj    = (float*) alloc((size_t)N * 128 * 4);
  __half* projh   = (__half*)alloc((size_t)N * 128 * 2);
  float*  skip1   = (float*) alloc((size_t)N * 128 * 4);
  float*  hbuf    = (float*) alloc((size_t)N * 128 * 4);
  float*  ssrc    = (float*) alloc((size_t)N * 8 * 4);
  float*  strg    = (float*) alloc((size_t)N * 8 * 4);
  (void)ws_size; (void)n_in; (void)out_size;

  hipMemsetAsync(degcur, 0, (size_t)2 * N * 4, stream);

  const int eb = (E + 255) / 256;
  const int gb = (N + 63) / 64;
  const int nb = (N + 255) / 256;   // scan blocks (196 for N=50000; must be <=256)

  // CSR build (shared by both layers)
  count_deg<<<eb, 256, 0, stream>>>(trgA, deg, E);
  scan_bsum<<<nb, 256, 0, stream>>>(deg, bsum, N);
  scan_top<<<1, 256, 0, stream>>>(bsum, boff, row_off, nb, N);
  scan_local<<<nb, 256, 0, stream>>>(deg, boff, row_off, N);
  scatter_csr<<<eb, 256, 0, stream>>>(srcA, trgA, ep, row_off, cursor, edge2, E);

  // -------- Layer 1: H=8, F=16, concat, skip = x @ Wskip1 --------
  gemm128_f32<<<gb, 256, 0, stream>>>(x, W1, proj, projh, N);
  gemm128_f32<<<gb, 256, 0, stream>>>(x, Wskip1, skip1, (__half*)nullptr, N);
  node_scores<8, 16><<<(N * 8 + 255) / 256, 256, 0, stream>>>(proj, a_src1, a_trg1, ssrc, strg, N);
  aggregate<8, 16><<<(N + 3) / 4, 256, 0, stream>>>(edge2, row_off, ssrc, strg, Wt1, a_tp1,
                                                    projh, skip1, b1, hbuf, N);

  // -------- Layer 2: H=1, F=128, mean (=identity), skip = identity --------
  gemm128_f32<<<gb, 256, 0, stream>>>(hbuf, W2, proj, projh, N);
  node_scores<1, 128><<<(N + 255) / 256, 256, 0, stream>>>(proj, a_src2, a_trg2, ssrc, strg, N);
  aggregate<1, 128><<<(N + 3) / 4, 256, 0, stream>>>(edge2, row_off, ssrc, strg, Wt2, a_tp2,
                                                     projh, hbuf, b2, (float*)d_out, N);
}

// Round 9
// 407.284 us; speedup vs baseline: 1.4450x; 1.0673x over previous
//
#include <hip/hip_runtime.h>
#include <hip/hip_fp16.h>
#include <cstdint>
#include <cstddef>

// ---------------------------------------------------------------------------
// GEMM: C[M,128] = A[M,128] @ B[128,128], fp32, 64x128 block tile, BK=32,
// 4x8 per thread. Thread tx owns cols {4tx..4tx+3} and {64+4tx..64+4tx+3}
// -> both Bs b128 reads span banks 0..31 (2-way = free), no 4-way conflict.
// Optionally writes an fp16 copy (Ch) for the gather path.
// ---------------------------------------------------------------------------
__global__ __launch_bounds__(256) void gemm128_f32(const float* __restrict__ A,
                                                   const float* __restrict__ B,
                                                   float* __restrict__ C,
                                                   __half* __restrict__ Ch, int M) {
  __shared__ float Ast[32][68];   // [k][row], 64 rows +4 pad
  __shared__ float Bs[32][132];   // [k][col], 128 cols +4 pad
  const int t = threadIdx.x;      // 256 threads
  const int row0 = blockIdx.x * 64;
  const int ty = t >> 4, tx = t & 15;  // 16x16 thread grid

  float acc[4][8] = {};

  for (int kt = 0; kt < 4; ++kt) {
#pragma unroll
    for (int i = 0; i < 2; ++i) {
      int idx = t + i * 256;           // 0..511
      int r = idx >> 3;                // 0..63
      int kq = (idx & 7) * 4;          // 0,4,..,28
      float4 v = make_float4(0.f, 0.f, 0.f, 0.f);
      if (row0 + r < M)
        v = *reinterpret_cast<const float4*>(A + (size_t)(row0 + r) * 128 + kt * 32 + kq);
      Ast[kq + 0][r] = v.x;
      Ast[kq + 1][r] = v.y;
      Ast[kq + 2][r] = v.z;
      Ast[kq + 3][r] = v.w;
    }
#pragma unroll
    for (int i = 0; i < 4; ++i) {
      int idx = t + i * 256;
      int k = idx >> 5;                // 0..31
      int c4 = (idx & 31) * 4;         // 0..124
      *reinterpret_cast<float4*>(&Bs[k][c4]) =
          *reinterpret_cast<const float4*>(B + (size_t)(kt * 32 + k) * 128 + c4);
    }
    __syncthreads();

#pragma unroll
    for (int k = 0; k < 32; ++k) {
      float4 a4 = *reinterpret_cast<float4*>(&Ast[k][ty * 4]);
      float4 b0 = *reinterpret_cast<float4*>(&Bs[k][tx * 4]);        // cols 4tx..4tx+3
      float4 b1 = *reinterpret_cast<float4*>(&Bs[k][64 + tx * 4]);   // cols 64+4tx..
      float a[4] = {a4.x, a4.y, a4.z, a4.w};
      float b[8] = {b0.x, b0.y, b0.z, b0.w, b1.x, b1.y, b1.z, b1.w};
#pragma unroll
      for (int i = 0; i < 4; ++i)
#pragma unroll
        for (int j = 0; j < 8; ++j) acc[i][j] += a[i] * b[j];
    }
    __syncthreads();
  }

#pragma unroll
  for (int i = 0; i < 4; ++i) {
    int r = row0 + ty * 4 + i;
    if (r < M) {
      float4 lo = make_float4(acc[i][0], acc[i][1], acc[i][2], acc[i][3]);
      float4 hi = make_float4(acc[i][4], acc[i][5], acc[i][6], acc[i][7]);
      *reinterpret_cast<float4*>(C + (size_t)r * 128 + tx * 4) = lo;
      *reinterpret_cast<float4*>(C + (size_t)r * 128 + 64 + tx * 4) = hi;
      if (Ch) {
        __half2* hp0 = reinterpret_cast<__half2*>(Ch + (size_t)r * 128 + tx * 4);
        __half2* hp1 = reinterpret_cast<__half2*>(Ch + (size_t)r * 128 + 64 + tx * 4);
        hp0[0] = __floats2half2_rn(lo.x, lo.y);
        hp0[1] = __floats2half2_rn(lo.z, lo.w);
        hp1[0] = __floats2half2_rn(hi.x, hi.y);
        hp1[1] = __floats2half2_rn(hi.z, hi.w);
      }
    }
  }
}

// ---------------------------------------------------------------------------
// CSR build: count -> hierarchical scan -> TWO-PASS BUCKETED scatter.
// Bucket b = trg>>8 (256 nodes/bucket); bucket base = row_off[b<<8] (exact).
// ---------------------------------------------------------------------------
__global__ void count_deg(const int* __restrict__ trg, int* __restrict__ deg, int E) {
  int e = blockIdx.x * blockDim.x + threadIdx.x;
  if (e < E) atomicAdd(&deg[trg[e]], 1);
}

__global__ void scan_bsum(const int* __restrict__ deg, int* __restrict__ bsum, int N) {
  __shared__ int ws[4];
  int i = blockIdx.x * 256 + threadIdx.x;
  int v = (i < N) ? deg[i] : 0;
#pragma unroll
  for (int off = 1; off < 64; off <<= 1) v += __shfl_xor(v, off);
  if ((threadIdx.x & 63) == 0) ws[threadIdx.x >> 6] = v;
  __syncthreads();
  if (threadIdx.x == 0) bsum[blockIdx.x] = ws[0] + ws[1] + ws[2] + ws[3];
}

__global__ void scan_top(const int* __restrict__ bsum, int* __restrict__ boff,
                         int* __restrict__ row_off, int nb, int N) {
  __shared__ int s[256];
  int t = threadIdx.x;
  int v = (t < nb) ? bsum[t] : 0;
  s[t] = v;
  __syncthreads();
#pragma unroll
  for (int off = 1; off < 256; off <<= 1) {
    int x = s[t];
    int add = (t >= off) ? s[t - off] : 0;
    __syncthreads();
    s[t] = x + add;
    __syncthreads();
  }
  if (t < nb) boff[t] = (t == 0) ? 0 : s[t - 1];
  if (t == 0) row_off[N] = s[255];
}

__global__ void scan_local(const int* __restrict__ deg, const int* __restrict__ boff,
                           int* __restrict__ row_off, int N) {
  __shared__ int s[256];
  int t = threadIdx.x;
  int i = blockIdx.x * 256 + t;
  int v = (i < N) ? deg[i] : 0;
  s[t] = v;
  __syncthreads();
#pragma unroll
  for (int off = 1; off < 256; off <<= 1) {
    int x = s[t];
    int add = (t >= off) ? s[t - off] : 0;
    __syncthreads();
    s[t] = x + add;
    __syncthreads();
  }
  if (i < N) row_off[i] = boff[blockIdx.x] + (t == 0 ? 0 : s[t - 1]);
}

// Pass A: LDS-binned scatter into bucket-contiguous staging.
// Payload: x = src(16b) | local_node(8b)<<16, y = ep bits.
__global__ __launch_bounds__(256) void bucket_scatter(
    const int* __restrict__ src, const int* __restrict__ trg,
    const float* __restrict__ ep, const int* __restrict__ row_off,
    int* __restrict__ bcur, int2* __restrict__ staging, int E, int N) {
  __shared__ int cnt[256], boff[256], rowb[256];
  const int nb2 = (N + 255) >> 8;
  if (threadIdx.x < nb2) cnt[threadIdx.x] = 0;
  __syncthreads();
  const int base = blockIdx.x * 1024;
  int b_[4], r_[4], s_[4], p_[4];
#pragma unroll
  for (int j = 0; j < 4; ++j) {
    int e = base + threadIdx.x + j * 256;
    bool v = e < E;
    int tg = v ? trg[e] : 0;
    int sc = v ? src[e] : 0;
    p_[j] = v ? __float_as_int(ep[e]) : 0;
    b_[j] = tg >> 8;
    s_[j] = sc | ((tg & 255) << 16);
    r_[j] = v ? atomicAdd(&cnt[b_[j]], 1) : -1;
  }
  __syncthreads();
  if (threadIdx.x < nb2) {
    int c = cnt[threadIdx.x];
    boff[threadIdx.x] = c ? atomicAdd(&bcur[threadIdx.x], c) : 0;
    rowb[threadIdx.x] = row_off[threadIdx.x << 8];
  }
  __syncthreads();
#pragma unroll
  for (int j = 0; j < 4; ++j) {
    if (r_[j] >= 0) {
      int b = b_[j];
      staging[(size_t)rowb[b] + boff[b] + r_[j]] = make_int2(s_[j], p_[j]);
    }
  }
}

// Pass B: one block per bucket; per-node cursors in LDS; writes stay inside
// the bucket's contiguous CSR span (L2-resident).
__global__ __launch_bounds__(256) void bucket_place(
    const int2* __restrict__ staging, const int* __restrict__ row_off,
    int2* __restrict__ edge2, int N) {
  __shared__ int cur[256];
  __shared__ int rbase[256];
  const int n0 = blockIdx.x << 8;
  const int nn = min(256, N - n0);
  if (threadIdx.x < nn) {
    cur[threadIdx.x] = 0;
    rbase[threadIdx.x] = row_off[n0 + threadIdx.x];
  }
  __syncthreads();
  const int lo = row_off[n0];
  const int hi = row_off[min(n0 + 256, N)];
  for (int i = lo + threadIdx.x; i < hi; i += 256) {
    int2 v = staging[i];
    int ln = (v.x >> 16) & 255;
    int pos = rbase[ln] + atomicAdd(&cur[ln], 1);
    edge2[pos] = make_int2(v.x & 0xFFFF, v.y);
  }
}

// ---------------------------------------------------------------------------
// Per-node attention scores (unchanged; reads fp32 proj)
// ---------------------------------------------------------------------------
template <int H, int F>
__global__ void node_scores(const float* __restrict__ proj, const float* __restrict__ a_src,
                            const float* __restrict__ a_trg, float* __restrict__ ssrc,
                            float* __restrict__ strg, int N) {
  int idx = blockIdx.x * blockDim.x + threadIdx.x;
  if (idx >= N * H) return;
  int n = idx / H, h = idx % H;
  const float* p = proj + (size_t)n * (H * F) + h * F;
  const float* as = a_src + h * F;
  const float* at = a_trg + h * F;
  float d1 = 0.f, d2 = 0.f;
#pragma unroll
  for (int f = 0; f < F; f += 4) {
    float4 pv = *reinterpret_cast<const float4*>(p + f);
    float4 av = *reinterpret_cast<const float4*>(as + f);
    float4 tv = *reinterpret_cast<const float4*>(at + f);
    d1 += pv.x * av.x + pv.y * av.y + pv.z * av.z + pv.w * av.w;
    d2 += pv.x * tv.x + pv.y * tv.y + pv.z * tv.z + pv.w * tv.w;
  }
  ssrc[idx] = d1;
  strg[idx] = d2;
}

// ---------------------------------------------------------------------------
// Fused aggregation (unchanged from R7): one wave per target node, single
// pass, inline scores, fp16 proj gather (256B/row).
// ---------------------------------------------------------------------------
template <int H, int F>
__global__ void aggregate(const int2* __restrict__ edge2, const int* __restrict__ row_off,
                          const float* __restrict__ ssrc, const float* __restrict__ strg,
                          const float* __restrict__ Wt, const float* __restrict__ a_tp,
                          const __half* __restrict__ projh, const float* __restrict__ skip,
                          const float* __restrict__ bias, float* __restrict__ out, int N) {
  int wid = (blockIdx.x * blockDim.x + threadIdx.x) >> 6;
  if (wid >= N) return;
  const int lane = threadIdx.x & 63;
  const int half = lane >> 5;        // 0 or 1
  const int fl = (lane & 31) * 4;    // feature base (4 consecutive features)
  const int h = fl / F;              // this lane's head

  float4 wt4 = *reinterpret_cast<const float4*>(Wt + fl);
  float4 at4 = *reinterpret_cast<const float4*>(a_tp + fl);
  float ch = wt4.x * at4.x + wt4.y * at4.y + wt4.z * at4.z + wt4.w * at4.w;
#pragma unroll
  for (int off = 1; off < (F / 4); off <<= 1) ch += __shfl_xor(ch, off);

  const float mt = strg[(size_t)wid * H + h];
  const int beg = row_off[wid];
  const int end = row_off[wid + 1];

  float ax = 0.f, ay = 0.f, az = 0.f, aw = 0.f;
  float denom = 0.f;

  for (int i = beg; i < end; i += 8) {
    int   s[4];
    float pe[4], vd[4];
    float2 raw[4];
#pragma unroll
    for (int q = 0; q < 4; ++q) {
      int ii = i + q * 2 + half;
      bool v = ii < end;
      int2 e2 = v ? edge2[ii] : make_int2(0, 0);
      s[q] = e2.x;
      pe[q] = __int_as_float(e2.y);
      vd[q] = v ? 1.f : 0.f;
    }
#pragma unroll
    for (int q = 0; q < 4; ++q)
      raw[q] = *reinterpret_cast<const float2*>(projh + (size_t)s[q] * (H * F) + fl);
#pragma unroll
    for (int q = 0; q < 4; ++q) {
      float sc = ssrc[(size_t)s[q] * H + h] + mt + pe[q] * ch;
      sc = sc > 0.f ? sc : 0.2f * sc;
      float ee = __expf(sc) * vd[q];
      __half2 h01 = *reinterpret_cast<__half2*>(&raw[q].x);
      __half2 h23 = *reinterpret_cast<__half2*>(&raw[q].y);
      float2 f01 = __half22float2(h01);
      float2 f23 = __half22float2(h23);
      denom += ee;
      ax += f01.x * ee;
      ay += f01.y * ee;
      az += f23.x * ee;
      aw += f23.y * ee;
    }
  }

  denom += __shfl_xor(denom, 32);
  ax += __shfl_xor(ax, 32);
  ay += __shfl_xor(ay, 32);
  az += __shfl_xor(az, 32);
  aw += __shfl_xor(aw, 32);

  if (half == 0) {
    float inv = 1.0f / (denom + 1e-16f);
    size_t base = (size_t)wid * (H * F) + fl;
    float4 sk = *reinterpret_cast<const float4*>(skip + base);
    float4 bi = *reinterpret_cast<const float4*>(bias + fl);
    float o0 = ax * inv + sk.x + bi.x;
    float o1 = ay * inv + sk.y + bi.y;
    float o2 = az * inv + sk.z + bi.z;
    float o3 = aw * inv + sk.w + bi.w;
    o0 = o0 > 0.f ? o0 : __expf(o0) - 1.f;
    o1 = o1 > 0.f ? o1 : __expf(o1) - 1.f;
    o2 = o2 > 0.f ? o2 : __expf(o2) - 1.f;
    o3 = o3 > 0.f ? o3 : __expf(o3) - 1.f;
    float4 ov = make_float4(o0, o1, o2, o3);
    *reinterpret_cast<float4*>(out + base) = ov;
  }
}

// ---------------------------------------------------------------------------
extern "C" void kernel_launch(void* const* d_in, const int* in_sizes, int n_in,
                              void* d_out, int out_size, void* d_ws, size_t ws_size,
                              hipStream_t stream) {
  const float* x      = (const float*)d_in[0];
  const int*   ei     = (const int*)  d_in[1];
  const float* ep     = (const float*)d_in[2];
  const float* W1     = (const float*)d_in[3];
  const float* Wt1    = (const float*)d_in[4];
  const float* a_src1 = (const float*)d_in[5];
  const float* a_trg1 = (const float*)d_in[6];
  const float* a_tp1  = (const float*)d_in[7];
  const float* b1     = (const float*)d_in[8];
  const float* Wskip1 = (const float*)d_in[9];
  const float* W2     = (const float*)d_in[10];
  const float* Wt2    = (const float*)d_in[11];
  const float* a_src2 = (const float*)d_in[12];
  const float* a_trg2 = (const float*)d_in[13];
  const float* a_tp2  = (const float*)d_in[14];
  const float* b2     = (const float*)d_in[15];

  const int N = in_sizes[0] / 128;
  const int E = in_sizes[1] / 2;
  const int* srcA = ei;
  const int* trgA = ei + E;

  char* ws = (char*)d_ws;
  size_t off = 0;
  auto alloc = [&](size_t bytes) {
    void* p = ws + off;
    off += (bytes + 255) & ~(size_t)255;
    return p;
  };
  int*    deg     = (int*)   alloc((size_t)(N + 256) * 4);  // deg | bcur (one memset)
  int*    bcur    = deg + N;
  int*    row_off = (int*)   alloc((size_t)(N + 1) * 4);
  int*    bsum    = (int*)   alloc((size_t)256 * 4);
  int*    boff    = (int*)   alloc((size_t)256 * 4);
  int2*   staging = (int2*)  alloc((size_t)E * 8);
  int2*   edge2   = (int2*)  alloc((size_t)E * 8);
  float*  proj    = (float*) alloc((size_t)N * 128 * 4);
  __half* projh   = (__half*)alloc((size_t)N * 128 * 2);
  float*  skip1   = (float*) alloc((size_t)N * 128 * 4);
  float*  hbuf    = (float*) alloc((size_t)N * 128 * 4);
  float*  ssrc    = (float*) alloc((size_t)N * 8 * 4);
  float*  strg    = (float*) alloc((size_t)N * 8 * 4);
  (void)ws_size; (void)n_in; (void)out_size;

  hipMemsetAsync(deg, 0, (size_t)(N + 256) * 4, stream);

  const int eb = (E + 255) / 256;
  const int gb = (N + 63) / 64;
  const int nb = (N + 255) / 256;   // 196 for N=50000 (<=256 required)

  // CSR build (shared by both layers)
  count_deg<<<eb, 256, 0, stream>>>(trgA, deg, E);
  scan_bsum<<<nb, 256, 0, stream>>>(deg, bsum, N);
  scan_top<<<1, 256, 0, stream>>>(bsum, boff, row_off, nb, N);
  scan_local<<<nb, 256, 0, stream>>>(deg, boff, row_off, N);
  bucket_scatter<<<(E + 1023) / 1024, 256, 0, stream>>>(srcA, trgA, ep, row_off, bcur,
                                                        staging, E, N);
  bucket_place<<<nb, 256, 0, stream>>>(staging, row_off, edge2, N);

  // -------- Layer 1: H=8, F=16, concat, skip = x @ Wskip1 --------
  gemm128_f32<<<gb, 256, 0, stream>>>(x, W1, proj, projh, N);
  gemm128_f32<<<gb, 256, 0, stream>>>(x, Wskip1, skip1, (__half*)nullptr, N);
  node_scores<8, 16><<<(N * 8 + 255) / 256, 256, 0, stream>>>(proj, a_src1, a_trg1, ssrc, strg, N);
  aggregate<8, 16><<<(N + 3) / 4, 256, 0, stream>>>(edge2, row_off, ssrc, strg, Wt1, a_tp1,
                                                    projh, skip1, b1, hbuf, N);

  // -------- Layer 2: H=1, F=128, mean (=identity), skip = identity --------
  gemm128_f32<<<gb, 256, 0, stream>>>(hbuf, W2, proj, projh, N);
  node_scores<1, 128><<<(N + 255) / 256, 256, 0, stream>>>(proj, a_src2, a_trg2, ssrc, strg, N);
  aggregate<1, 128><<<(N + 3) / 4, 256, 0, stream>>>(edge2, row_off, ssrc, strg, Wt2, a_tp2,
                                                     projh, hbuf, b2, (float*)d_out, N);
}

// Round 11
// 405.433 us; speedup vs baseline: 1.4516x; 1.0046x over previous
//
#include <hip/hip_runtime.h>
#include <hip/hip_fp16.h>
#include <cstdint>
#include <cstddef>

// ---------------------------------------------------------------------------
// Dual GEMM (layer 1): C1 = A@B1 (+fp16 copy Ch1), C2 = A@B2. A read once.
// 64x128 tile, BK=32, 4x8 per thread per output. 42.5 KB LDS.
// ---------------------------------------------------------------------------
__global__ __launch_bounds__(256) void gemm_dual(const float* __restrict__ A,
                                                 const float* __restrict__ B1,
                                                 const float* __restrict__ B2,
                                                 float* __restrict__ C1,
                                                 __half* __restrict__ Ch1,
                                                 float* __restrict__ C2, int M) {
  __shared__ float Ast[32][68];
  __shared__ float Bs1[32][132];
  __shared__ float Bs2[32][132];
  const int t = threadIdx.x;
  const int row0 = blockIdx.x * 64;
  const int ty = t >> 4, tx = t & 15;

  float acc1[4][8] = {};
  float acc2[4][8] = {};

  for (int kt = 0; kt < 4; ++kt) {
#pragma unroll
    for (int i = 0; i < 2; ++i) {
      int idx = t + i * 256;
      int r = idx >> 3;
      int kq = (idx & 7) * 4;
      float4 v = make_float4(0.f, 0.f, 0.f, 0.f);
      if (row0 + r < M)
        v = *reinterpret_cast<const float4*>(A + (size_t)(row0 + r) * 128 + kt * 32 + kq);
      Ast[kq + 0][r] = v.x;
      Ast[kq + 1][r] = v.y;
      Ast[kq + 2][r] = v.z;
      Ast[kq + 3][r] = v.w;
    }
#pragma unroll
    for (int i = 0; i < 4; ++i) {
      int idx = t + i * 256;
      int k = idx >> 5;
      int c4 = (idx & 31) * 4;
      *reinterpret_cast<float4*>(&Bs1[k][c4]) =
          *reinterpret_cast<const float4*>(B1 + (size_t)(kt * 32 + k) * 128 + c4);
      *reinterpret_cast<float4*>(&Bs2[k][c4]) =
          *reinterpret_cast<const float4*>(B2 + (size_t)(kt * 32 + k) * 128 + c4);
    }
    __syncthreads();

#pragma unroll
    for (int k = 0; k < 32; ++k) {
      float4 a4 = *reinterpret_cast<float4*>(&Ast[k][ty * 4]);
      float a[4] = {a4.x, a4.y, a4.z, a4.w};
      float4 p0 = *reinterpret_cast<float4*>(&Bs1[k][tx * 4]);
      float4 p1 = *reinterpret_cast<float4*>(&Bs1[k][64 + tx * 4]);
      float b1v[8] = {p0.x, p0.y, p0.z, p0.w, p1.x, p1.y, p1.z, p1.w};
      float4 q0 = *reinterpret_cast<float4*>(&Bs2[k][tx * 4]);
      float4 q1 = *reinterpret_cast<float4*>(&Bs2[k][64 + tx * 4]);
      float b2v[8] = {q0.x, q0.y, q0.z, q0.w, q1.x, q1.y, q1.z, q1.w};
#pragma unroll
      for (int i = 0; i < 4; ++i)
#pragma unroll
        for (int j = 0; j < 8; ++j) {
          acc1[i][j] += a[i] * b1v[j];
          acc2[i][j] += a[i] * b2v[j];
        }
    }
    __syncthreads();
  }

#pragma unroll
  for (int i = 0; i < 4; ++i) {
    int r = row0 + ty * 4 + i;
    if (r < M) {
      float4 lo = make_float4(acc1[i][0], acc1[i][1], acc1[i][2], acc1[i][3]);
      float4 hi = make_float4(acc1[i][4], acc1[i][5], acc1[i][6], acc1[i][7]);
      *reinterpret_cast<float4*>(C1 + (size_t)r * 128 + tx * 4) = lo;
      *reinterpret_cast<float4*>(C1 + (size_t)r * 128 + 64 + tx * 4) = hi;
      __half2* hp0 = reinterpret_cast<__half2*>(Ch1 + (size_t)r * 128 + tx * 4);
      __half2* hp1 = reinterpret_cast<__half2*>(Ch1 + (size_t)r * 128 + 64 + tx * 4);
      hp0[0] = __floats2half2_rn(lo.x, lo.y);
      hp0[1] = __floats2half2_rn(lo.z, lo.w);
      hp1[0] = __floats2half2_rn(hi.x, hi.y);
      hp1[1] = __floats2half2_rn(hi.z, hi.w);
      float4 lo2 = make_float4(acc2[i][0], acc2[i][1], acc2[i][2], acc2[i][3]);
      float4 hi2 = make_float4(acc2[i][4], acc2[i][5], acc2[i][6], acc2[i][7]);
      *reinterpret_cast<float4*>(C2 + (size_t)r * 128 + tx * 4) = lo2;
      *reinterpret_cast<float4*>(C2 + (size_t)r * 128 + 64 + tx * 4) = hi2;
    }
  }
}

// ---------------------------------------------------------------------------
// Single GEMM (layer 2), unchanged from R9.
// ---------------------------------------------------------------------------
__global__ __launch_bounds__(256) void gemm128_f32(const float* __restrict__ A,
                                                   const float* __restrict__ B,
                                                   float* __restrict__ C,
                                                   __half* __restrict__ Ch, int M) {
  __shared__ float Ast[32][68];
  __shared__ float Bs[32][132];
  const int t = threadIdx.x;
  const int row0 = blockIdx.x * 64;
  const int ty = t >> 4, tx = t & 15;

  float acc[4][8] = {};

  for (int kt = 0; kt < 4; ++kt) {
#pragma unroll
    for (int i = 0; i < 2; ++i) {
      int idx = t + i * 256;
      int r = idx >> 3;
      int kq = (idx & 7) * 4;
      float4 v = make_float4(0.f, 0.f, 0.f, 0.f);
      if (row0 + r < M)
        v = *reinterpret_cast<const float4*>(A + (size_t)(row0 + r) * 128 + kt * 32 + kq);
      Ast[kq + 0][r] = v.x;
      Ast[kq + 1][r] = v.y;
      Ast[kq + 2][r] = v.z;
      Ast[kq + 3][r] = v.w;
    }
#pragma unroll
    for (int i = 0; i < 4; ++i) {
      int idx = t + i * 256;
      int k = idx >> 5;
      int c4 = (idx & 31) * 4;
      *reinterpret_cast<float4*>(&Bs[k][c4]) =
          *reinterpret_cast<const float4*>(B + (size_t)(kt * 32 + k) * 128 + c4);
    }
    __syncthreads();

#pragma unroll
    for (int k = 0; k < 32; ++k) {
      float4 a4 = *reinterpret_cast<float4*>(&Ast[k][ty * 4]);
      float4 b0 = *reinterpret_cast<float4*>(&Bs[k][tx * 4]);
      float4 b1 = *reinterpret_cast<float4*>(&Bs[k][64 + tx * 4]);
      float a[4] = {a4.x, a4.y, a4.z, a4.w};
      float b[8] = {b0.x, b0.y, b0.z, b0.w, b1.x, b1.y, b1.z, b1.w};
#pragma unroll
      for (int i = 0; i < 4; ++i)
#pragma unroll
        for (int j = 0; j < 8; ++j) acc[i][j] += a[i] * b[j];
    }
    __syncthreads();
  }

#pragma unroll
  for (int i = 0; i < 4; ++i) {
    int r = row0 + ty * 4 + i;
    if (r < M) {
      float4 lo = make_float4(acc[i][0], acc[i][1], acc[i][2], acc[i][3]);
      float4 hi = make_float4(acc[i][4], acc[i][5], acc[i][6], acc[i][7]);
      *reinterpret_cast<float4*>(C + (size_t)r * 128 + tx * 4) = lo;
      *reinterpret_cast<float4*>(C + (size_t)r * 128 + 64 + tx * 4) = hi;
      if (Ch) {
        __half2* hp0 = reinterpret_cast<__half2*>(Ch + (size_t)r * 128 + tx * 4);
        __half2* hp1 = reinterpret_cast<__half2*>(Ch + (size_t)r * 128 + 64 + tx * 4);
        hp0[0] = __floats2half2_rn(lo.x, lo.y);
        hp0[1] = __floats2half2_rn(lo.z, lo.w);
        hp1[0] = __floats2half2_rn(hi.x, hi.y);
        hp1[1] = __floats2half2_rn(hi.z, hi.w);
      }
    }
  }
}

// ---------------------------------------------------------------------------
// CSR build v3: LDS bucket histogram -> tiny scan -> bucketed scatter ->
// bucket_place (computes per-node offsets in-block, writes row_off + edge2).
// No per-node global atomics, no N-wide scan.
// ---------------------------------------------------------------------------
__global__ __launch_bounds__(256) void bucket_hist(const int* __restrict__ trg,
                                                   int* __restrict__ bhist, int E) {
  __shared__ int cnt[256];
  cnt[threadIdx.x] = 0;
  __syncthreads();
  const int base = blockIdx.x * 1024;
#pragma unroll
  for (int j = 0; j < 4; ++j) {
    int e = base + threadIdx.x + j * 256;
    if (e < E) atomicAdd(&cnt[trg[e] >> 8], 1);
  }
  __syncthreads();
  int c = cnt[threadIdx.x];
  if (c) atomicAdd(&bhist[threadIdx.x], c);
}

// One block: exclusive scan of bhist (nb<=256) -> boffx[0..nb] (boffx[nb]=E);
// also zeroes bcur and writes row_off[N].
__global__ void scan196(const int* __restrict__ bhist, int* __restrict__ boffx,
                        int* __restrict__ bcur, int* __restrict__ row_off, int nb, int N) {
  __shared__ int s[256];
  int t = threadIdx.x;
  bcur[t] = 0;
  int v = (t < nb) ? bhist[t] : 0;
  s[t] = v;
  __syncthreads();
#pragma unroll
  for (int off = 1; off < 256; off <<= 1) {
    int x = s[t];
    int add = (t >= off) ? s[t - off] : 0;
    __syncthreads();
    s[t] = x + add;
    __syncthreads();
  }
  if (t < nb) boffx[t] = (t == 0) ? 0 : s[t - 1];
  if (t == 0) {
    boffx[nb] = s[255];
    row_off[N] = s[255];
  }
}

// Pass A: LDS-binned scatter into bucket-contiguous staging.
// Payload: x = src(16b) | local_node(8b)<<16, y = ep bits.
__global__ __launch_bounds__(256) void bucket_scatter(
    const int* __restrict__ src, const int* __restrict__ trg,
    const float* __restrict__ ep, const int* __restrict__ boffx,
    int* __restrict__ bcur, int2* __restrict__ staging, int E, int N) {
  __shared__ int cnt[256], boff[256], rowb[256];
  const int nb2 = (N + 255) >> 8;
  if (threadIdx.x < nb2) cnt[threadIdx.x] = 0;
  __syncthreads();
  const int base = blockIdx.x * 1024;
  int b_[4], r_[4], s_[4], p_[4];
#pragma unroll
  for (int j = 0; j < 4; ++j) {
    int e = base + threadIdx.x + j * 256;
    bool v = e < E;
    int tg = v ? trg[e] : 0;
    int sc = v ? src[e] : 0;
    p_[j] = v ? __float_as_int(ep[e]) : 0;
    b_[j] = tg >> 8;
    s_[j] = sc | ((tg & 255) << 16);
    r_[j] = v ? atomicAdd(&cnt[b_[j]], 1) : -1;
  }
  __syncthreads();
  if (threadIdx.x < nb2) {
    int c = cnt[threadIdx.x];
    boff[threadIdx.x] = c ? atomicAdd(&bcur[threadIdx.x], c) : 0;
    rowb[threadIdx.x] = boffx[threadIdx.x];
  }
  __syncthreads();
#pragma unroll
  for (int j = 0; j < 4; ++j) {
    if (r_[j] >= 0) {
      int b = b_[j];
      staging[rowb[b] + boff[b] + r_[j]] = make_int2(s_[j], p_[j]);
    }
  }
}

// Pass B: one block per bucket. LDS histogram of local node ids + in-block
// scan -> per-node offsets (row_off written here); then place edges.
__global__ __launch_bounds__(256) void bucket_place(
    const int2* __restrict__ staging, const int* __restrict__ boffx,
    int* __restrict__ row_off, int2* __restrict__ edge2, int N) {
  __shared__ int cnt[256], loc[256], cur[256];
  const int t = threadIdx.x;
  const int n0 = blockIdx.x << 8;
  const int nn = min(256, N - n0);
  cnt[t] = 0;
  __syncthreads();
  const int lo = boffx[blockIdx.x];
  const int hi = boffx[blockIdx.x + 1];
  for (int i = lo + t; i < hi; i += 256) {
    atomicAdd(&cnt[(staging[i].x >> 16) & 255], 1);
  }
  __syncthreads();
  loc[t] = cnt[t];
  __syncthreads();
#pragma unroll
  for (int off = 1; off < 256; off <<= 1) {
    int x = loc[t];
    int add = (t >= off) ? loc[t - off] : 0;
    __syncthreads();
    loc[t] = x + add;
    __syncthreads();
  }
  int excl = loc[t] - cnt[t];
  if (t < nn) row_off[n0 + t] = lo + excl;
  cur[t] = lo + excl;  // running cursor for placement
  __syncthreads();
  for (int i = lo + t; i < hi; i += 256) {
    int2 v = staging[i];
    int ln = (v.x >> 16) & 255;
    int pos = atomicAdd(&cur[ln], 1);
    edge2[pos] = make_int2(v.x & 0xFFFF, v.y);
  }
}

// ---------------------------------------------------------------------------
// Per-node attention scores (unchanged)
// ---------------------------------------------------------------------------
template <int H, int F>
__global__ void node_scores(const float* __restrict__ proj, const float* __restrict__ a_src,
                            const float* __restrict__ a_trg, float* __restrict__ ssrc,
                            float* __restrict__ strg, int N) {
  int idx = blockIdx.x * blockDim.x + threadIdx.x;
  if (idx >= N * H) return;
  int n = idx / H, h = idx % H;
  const float* p = proj + (size_t)n * (H * F) + h * F;
  const float* as = a_src + h * F;
  const float* at = a_trg + h * F;
  float d1 = 0.f, d2 = 0.f;
#pragma unroll
  for (int f = 0; f < F; f += 4) {
    float4 pv = *reinterpret_cast<const float4*>(p + f);
    float4 av = *reinterpret_cast<const float4*>(as + f);
    float4 tv = *reinterpret_cast<const float4*>(at + f);
    d1 += pv.x * av.x + pv.y * av.y + pv.z * av.z + pv.w * av.w;
    d2 += pv.x * tv.x + pv.y * tv.y + pv.z * tv.z + pv.w * tv.w;
  }
  ssrc[idx] = d1;
  strg[idx] = d2;
}

// ---------------------------------------------------------------------------
// Fused aggregation: one wave per node, single pass, inline scores, fp16
// gather. 32-bit addressing: H*F==128 -> proj offset = (s<<7)+fl.
// ---------------------------------------------------------------------------
template <int H, int F>
__global__ void aggregate(const int2* __restrict__ edge2, const int* __restrict__ row_off,
                          const float* __restrict__ ssrc, const float* __restrict__ strg,
                          const float* __restrict__ Wt, const float* __restrict__ a_tp,
                          const __half* __restrict__ projh, const float* __restrict__ skip,
                          const float* __restrict__ bias, float* __restrict__ out, int N) {
  static_assert(H * F == 128, "offset shift assumes H*F==128");
  int wid = (blockIdx.x * blockDim.x + threadIdx.x) >> 6;
  if (wid >= N) return;
  const int lane = threadIdx.x & 63;
  const int half = lane >> 5;
  const int fl = (lane & 31) * 4;
  const int h = fl / F;

  float4 wt4 = *reinterpret_cast<const float4*>(Wt + fl);
  float4 at4 = *reinterpret_cast<const float4*>(a_tp + fl);
  float ch = wt4.x * at4.x + wt4.y * at4.y + wt4.z * at4.z + wt4.w * at4.w;
#pragma unroll
  for (int off = 1; off < (F / 4); off <<= 1) ch += __shfl_xor(ch, off);

  const float mt = strg[wid * H + h];
  const int beg = row_off[wid];
  const int end = row_off[wid + 1];

  float ax = 0.f, ay = 0.f, az = 0.f, aw = 0.f;
  float denom = 0.f;

  for (int i = beg; i < end; i += 8) {
    int   s[4];
    float pe[4], vd[4];
    float2 raw[4];
#pragma unroll
    for (int q = 0; q < 4; ++q) {
      int ii = i + q * 2 + half;
      bool v = ii < end;
      int2 e2 = v ? edge2[ii] : make_int2(0, 0);
      s[q] = e2.x;
      pe[q] = __int_as_float(e2.y);
      vd[q] = v ? 1.f : 0.f;
    }
#pragma unroll
    for (int q = 0; q < 4; ++q)
      raw[q] = *reinterpret_cast<const float2*>(projh + (s[q] << 7) + fl);
#pragma unroll
    for (int q = 0; q < 4; ++q) {
      float sc = ssrc[s[q] * H + h] + mt + pe[q] * ch;
      sc = sc > 0.f ? sc : 0.2f * sc;
      float ee = __expf(sc) * vd[q];
      __half2 h01 = *reinterpret_cast<__half2*>(&raw[q].x);
      __half2 h23 = *reinterpret_cast<__half2*>(&raw[q].y);
      float2 f01 = __half22float2(h01);
      float2 f23 = __half22float2(h23);
      denom += ee;
      ax += f01.x * ee;
      ay += f01.y * ee;
      az += f23.x * ee;
      aw += f23.y * ee;
    }
  }

  denom += __shfl_xor(denom, 32);
  ax += __shfl_xor(ax, 32);
  ay += __shfl_xor(ay, 32);
  az += __shfl_xor(az, 32);
  aw += __shfl_xor(aw, 32);

  if (half == 0) {
    float inv = 1.0f / (denom + 1e-16f);
    int base = (wid << 7) + fl;
    float4 sk = *reinterpret_cast<const float4*>(skip + base);
    float4 bi = *reinterpret_cast<const float4*>(bias + fl);
    float o0 = ax * inv + sk.x + bi.x;
    float o1 = ay * inv + sk.y + bi.y;
    float o2 = az * inv + sk.z + bi.z;
    float o3 = aw * inv + sk.w + bi.w;
    o0 = o0 > 0.f ? o0 : __expf(o0) - 1.f;
    o1 = o1 > 0.f ? o1 : __expf(o1) - 1.f;
    o2 = o2 > 0.f ? o2 : __expf(o2) - 1.f;
    o3 = o3 > 0.f ? o3 : __expf(o3) - 1.f;
    float4 ov = make_float4(o0, o1, o2, o3);
    *reinterpret_cast<float4*>(out + base) = ov;
  }
}

// ---------------------------------------------------------------------------
extern "C" void kernel_launch(void* const* d_in, const int* in_sizes, int n_in,
                              void* d_out, int out_size, void* d_ws, size_t ws_size,
                              hipStream_t stream) {
  const float* x      = (const float*)d_in[0];
  const int*   ei     = (const int*)  d_in[1];
  const float* ep     = (const float*)d_in[2];
  const float* W1     = (const float*)d_in[3];
  const float* Wt1    = (const float*)d_in[4];
  const float* a_src1 = (const float*)d_in[5];
  const float* a_trg1 = (const float*)d_in[6];
  const float* a_tp1  = (const float*)d_in[7];
  const float* b1     = (const float*)d_in[8];
  const float* Wskip1 = (const float*)d_in[9];
  const float* W2     = (const float*)d_in[10];
  const float* Wt2    = (const float*)d_in[11];
  const float* a_src2 = (const float*)d_in[12];
  const float* a_trg2 = (const float*)d_in[13];
  const float* a_tp2  = (const float*)d_in[14];
  const float* b2     = (const float*)d_in[15];

  const int N = in_sizes[0] / 128;
  const int E = in_sizes[1] / 2;
  const int* srcA = ei;
  const int* trgA = ei + E;

  char* ws = (char*)d_ws;
  size_t off = 0;
  auto alloc = [&](size_t bytes) {
    void* p = ws + off;
    off += (bytes + 255) & ~(size_t)255;
    return p;
  };
  int*    bhist   = (int*)   alloc((size_t)256 * 4);       // memset'd (1 KB)
  int*    bcur    = (int*)   alloc((size_t)256 * 4);       // zeroed by scan196
  int*    boffx   = (int*)   alloc((size_t)257 * 4);
  int*    row_off = (int*)   alloc((size_t)(N + 1) * 4);
  int2*   staging = (int2*)  alloc((size_t)E * 8);
  int2*   edge2   = (int2*)  alloc((size_t)E * 8);
  float*  proj    = (float*) alloc((size_t)N * 128 * 4);
  __half* projh   = (__half*)alloc((size_t)N * 128 * 2);
  float*  skip1   = (float*) alloc((size_t)N * 128 * 4);
  float*  hbuf    = (float*) alloc((size_t)N * 128 * 4);
  float*  ssrc    = (float*) alloc((size_t)N * 8 * 4);
  float*  strg    = (float*) alloc((size_t)N * 8 * 4);
  (void)ws_size; (void)n_in; (void)out_size;

  hipMemsetAsync(bhist, 0, 256 * 4, stream);

  const int eb4 = (E + 1023) / 1024;
  const int gb = (N + 63) / 64;
  const int nb = (N + 255) / 256;   // 196 for N=50000 (<=256 required)

  // CSR build (shared by both layers)
  bucket_hist<<<eb4, 256, 0, stream>>>(trgA, bhist, E);
  scan196<<<1, 256, 0, stream>>>(bhist, boffx, bcur, row_off, nb, N);
  bucket_scatter<<<eb4, 256, 0, stream>>>(srcA, trgA, ep, boffx, bcur, staging, E, N);
  bucket_place<<<nb, 256, 0, stream>>>(staging, boffx, row_off, edge2, N);

  // -------- Layer 1: H=8, F=16, concat, skip = x @ Wskip1 --------
  gemm_dual<<<gb, 256, 0, stream>>>(x, W1, Wskip1, proj, projh, skip1, N);
  node_scores<8, 16><<<(N * 8 + 255) / 256, 256, 0, stream>>>(proj, a_src1, a_trg1, ssrc, strg, N);
  aggregate<8, 16><<<(N + 3) / 4, 256, 0, stream>>>(edge2, row_off, ssrc, strg, Wt1, a_tp1,
                                                    projh, skip1, b1, hbuf, N);

  // -------- Layer 2: H=1, F=128, mean (=identity), skip = identity --------
  gemm128_f32<<<gb, 256, 0, stream>>>(hbuf, W2, proj, projh, N);
  node_scores<1, 128><<<(N + 255) / 256, 256, 0, stream>>>(proj, a_src2, a_trg2, ssrc, strg, N);
  aggregate<1, 128><<<(N + 3) / 4, 256, 0, stream>>>(edge2, row_off, ssrc, strg, Wt2, a_tp2,
                                                     projh, hbuf, b2, (float*)d_out, N);
}

// Round 12
// 344.790 us; speedup vs baseline: 1.7069x; 1.1759x over previous
//
#include <hip/hip_runtime.h>
#include <hip/hip_fp16.h>
#include <cstdint>
#include <cstddef>

typedef _Float16 half8 __attribute__((ext_vector_type(8)));
typedef float f32x4 __attribute__((ext_vector_type(4)));

// ---------------------------------------------------------------------------
// Pack 128x128 fp32 B into MFMA-fragment-ordered fp16:
// slot = (kt*8 + nt)*64 + lane; element j = B[kt*32 + (lane>>4)*8 + j][nt*16 + (lane&15)]
// ---------------------------------------------------------------------------
__global__ void pack_b(const float* __restrict__ B, __half* __restrict__ Bp) {
  int slot = blockIdx.x * 256 + threadIdx.x;   // grid 8 x 256 = 2048 slots
  int lane = slot & 63;
  int nt = (slot >> 6) & 7;
  int kt = slot >> 9;
  int r0 = kt * 32 + (lane >> 4) * 8;
  int col = nt * 16 + (lane & 15);
  __half tmp[8];
#pragma unroll
  for (int j = 0; j < 8; ++j) tmp[j] = __float2half(B[(r0 + j) * 128 + col]);
  *reinterpret_cast<float4*>(Bp + (size_t)slot * 8) = *reinterpret_cast<float4*>(tmp);
}

// fp32 -> fp16 bulk convert (8 els/thread)
__global__ void f32_to_f16(const float* __restrict__ in, __half* __restrict__ out, int n8) {
  int i = blockIdx.x * 256 + threadIdx.x;
  if (i >= n8) return;
  float4 a = *reinterpret_cast<const float4*>(in + (size_t)i * 8);
  float4 b = *reinterpret_cast<const float4*>(in + (size_t)i * 8 + 4);
  __half2 h[4] = {__floats2half2_rn(a.x, a.y), __floats2half2_rn(a.z, a.w),
                  __floats2half2_rn(b.x, b.y), __floats2half2_rn(b.z, b.w)};
  *reinterpret_cast<float4*>(out + (size_t)i * 8) = *reinterpret_cast<float4*>(h);
}

// ---------------------------------------------------------------------------
// MFMA GEMM: C[M,128] = A[M,128] @ B, fp16 in/out, fp32 accum. No LDS.
// Block: 256 thr = 4 waves; wave w owns rows blk*64 + w*16; 8 col-tiles.
// ---------------------------------------------------------------------------
__global__ __launch_bounds__(256) void gemm_mfma(const __half* __restrict__ Ah,
                                                 const half8* __restrict__ Bp,
                                                 __half* __restrict__ C, int M) {
  const int w = threadIdx.x >> 6, lane = threadIdx.x & 63;
  const int row0 = blockIdx.x * 64 + w * 16;
  const int arow = row0 + (lane & 15);
  const int kb = (lane >> 4) * 8;
  const bool av = arow < M;
  f32x4 acc[8] = {};
  for (int kt = 0; kt < 4; ++kt) {
    half8 af = {};
    if (av) af = *reinterpret_cast<const half8*>(Ah + (size_t)arow * 128 + kt * 32 + kb);
    const half8* bb = Bp + (kt * 8) * 64 + lane;
#pragma unroll
    for (int nt = 0; nt < 8; ++nt)
      acc[nt] = __builtin_amdgcn_mfma_f32_16x16x32_f16(af, bb[nt * 64], acc[nt], 0, 0, 0);
  }
  const int orow = row0 + (lane >> 4) * 4;
  const int col = lane & 15;
#pragma unroll
  for (int r = 0; r < 4; ++r) {
    int rr = orow + r;
    if (rr < M) {
#pragma unroll
      for (int nt = 0; nt < 8; ++nt)
        C[(size_t)rr * 128 + nt * 16 + col] = __float2half(acc[nt][r]);
    }
  }
}

// Dual-B variant (layer 1): shares the A fragment between W1 and Wskip.
__global__ __launch_bounds__(256) void gemm_mfma_dual(const __half* __restrict__ Ah,
                                                      const half8* __restrict__ Bp1,
                                                      const half8* __restrict__ Bp2,
                                                      __half* __restrict__ C1,
                                                      __half* __restrict__ C2, int M) {
  const int w = threadIdx.x >> 6, lane = threadIdx.x & 63;
  const int row0 = blockIdx.x * 64 + w * 16;
  const int arow = row0 + (lane & 15);
  const int kb = (lane >> 4) * 8;
  const bool av = arow < M;
  f32x4 acc1[8] = {};
  f32x4 acc2[8] = {};
  for (int kt = 0; kt < 4; ++kt) {
    half8 af = {};
    if (av) af = *reinterpret_cast<const half8*>(Ah + (size_t)arow * 128 + kt * 32 + kb);
    const half8* b1 = Bp1 + (kt * 8) * 64 + lane;
    const half8* b2 = Bp2 + (kt * 8) * 64 + lane;
#pragma unroll
    for (int nt = 0; nt < 8; ++nt) {
      acc1[nt] = __builtin_amdgcn_mfma_f32_16x16x32_f16(af, b1[nt * 64], acc1[nt], 0, 0, 0);
      acc2[nt] = __builtin_amdgcn_mfma_f32_16x16x32_f16(af, b2[nt * 64], acc2[nt], 0, 0, 0);
    }
  }
  const int orow = row0 + (lane >> 4) * 4;
  const int col = lane & 15;
#pragma unroll
  for (int r = 0; r < 4; ++r) {
    int rr = orow + r;
    if (rr < M) {
#pragma unroll
      for (int nt = 0; nt < 8; ++nt) {
        C1[(size_t)rr * 128 + nt * 16 + col] = __float2half(acc1[nt][r]);
        C2[(size_t)rr * 128 + nt * 16 + col] = __float2half(acc2[nt][r]);
      }
    }
  }
}

// ---------------------------------------------------------------------------
// CSR build v3 (unchanged from R11, verified passing)
// ---------------------------------------------------------------------------
__global__ __launch_bounds__(256) void bucket_hist(const int* __restrict__ trg,
                                                   int* __restrict__ bhist, int E) {
  __shared__ int cnt[256];
  cnt[threadIdx.x] = 0;
  __syncthreads();
  const int base = blockIdx.x * 1024;
#pragma unroll
  for (int j = 0; j < 4; ++j) {
    int e = base + threadIdx.x + j * 256;
    if (e < E) atomicAdd(&cnt[trg[e] >> 8], 1);
  }
  __syncthreads();
  int c = cnt[threadIdx.x];
  if (c) atomicAdd(&bhist[threadIdx.x], c);
}

__global__ void scan196(const int* __restrict__ bhist, int* __restrict__ boffx,
                        int* __restrict__ bcur, int* __restrict__ row_off, int nb, int N) {
  __shared__ int s[256];
  int t = threadIdx.x;
  bcur[t] = 0;
  int v = (t < nb) ? bhist[t] : 0;
  s[t] = v;
  __syncthreads();
#pragma unroll
  for (int off = 1; off < 256; off <<= 1) {
    int x = s[t];
    int add = (t >= off) ? s[t - off] : 0;
    __syncthreads();
    s[t] = x + add;
    __syncthreads();
  }
  if (t < nb) boffx[t] = (t == 0) ? 0 : s[t - 1];
  if (t == 0) {
    boffx[nb] = s[255];
    row_off[N] = s[255];
  }
}

__global__ __launch_bounds__(256) void bucket_scatter(
    const int* __restrict__ src, const int* __restrict__ trg,
    const float* __restrict__ ep, const int* __restrict__ boffx,
    int* __restrict__ bcur, int2* __restrict__ staging, int E, int N) {
  __shared__ int cnt[256], boff[256], rowb[256];
  const int nb2 = (N + 255) >> 8;
  if (threadIdx.x < nb2) cnt[threadIdx.x] = 0;
  __syncthreads();
  const int base = blockIdx.x * 1024;
  int b_[4], r_[4], s_[4], p_[4];
#pragma unroll
  for (int j = 0; j < 4; ++j) {
    int e = base + threadIdx.x + j * 256;
    bool v = e < E;
    int tg = v ? trg[e] : 0;
    int sc = v ? src[e] : 0;
    p_[j] = v ? __float_as_int(ep[e]) : 0;
    b_[j] = tg >> 8;
    s_[j] = sc | ((tg & 255) << 16);
    r_[j] = v ? atomicAdd(&cnt[b_[j]], 1) : -1;
  }
  __syncthreads();
  if (threadIdx.x < nb2) {
    int c = cnt[threadIdx.x];
    boff[threadIdx.x] = c ? atomicAdd(&bcur[threadIdx.x], c) : 0;
    rowb[threadIdx.x] = boffx[threadIdx.x];
  }
  __syncthreads();
#pragma unroll
  for (int j = 0; j < 4; ++j) {
    if (r_[j] >= 0) {
      int b = b_[j];
      staging[rowb[b] + boff[b] + r_[j]] = make_int2(s_[j], p_[j]);
    }
  }
}

__global__ __launch_bounds__(256) void bucket_place(
    const int2* __restrict__ staging, const int* __restrict__ boffx,
    int* __restrict__ row_off, int2* __restrict__ edge2, int N) {
  __shared__ int cnt[256], loc[256], cur[256];
  const int t = threadIdx.x;
  const int n0 = blockIdx.x << 8;
  const int nn = min(256, N - n0);
  cnt[t] = 0;
  __syncthreads();
  const int lo = boffx[blockIdx.x];
  const int hi = boffx[blockIdx.x + 1];
  for (int i = lo + t; i < hi; i += 256) {
    atomicAdd(&cnt[(staging[i].x >> 16) & 255], 1);
  }
  __syncthreads();
  loc[t] = cnt[t];
  __syncthreads();
#pragma unroll
  for (int off = 1; off < 256; off <<= 1) {
    int x = loc[t];
    int add = (t >= off) ? loc[t - off] : 0;
    __syncthreads();
    loc[t] = x + add;
    __syncthreads();
  }
  int excl = loc[t] - cnt[t];
  if (t < nn) row_off[n0 + t] = lo + excl;
  cur[t] = lo + excl;
  __syncthreads();
  for (int i = lo + t; i < hi; i += 256) {
    int2 v = staging[i];
    int ln = (v.x >> 16) & 255;
    int pos = atomicAdd(&cur[ln], 1);
    edge2[pos] = make_int2(v.x & 0xFFFF, v.y);
  }
}

// ---------------------------------------------------------------------------
// Per-node attention scores from fp16 proj
// ---------------------------------------------------------------------------
template <int H, int F>
__global__ void node_scores_h(const __half* __restrict__ projh, const float* __restrict__ a_src,
                              const float* __restrict__ a_trg, float* __restrict__ ssrc,
                              float* __restrict__ strg, int N) {
  int idx = blockIdx.x * blockDim.x + threadIdx.x;
  if (idx >= N * H) return;
  int n = idx / H, h = idx % H;
  const __half* p = projh + (size_t)n * (H * F) + h * F;
  const float* as = a_src + h * F;
  const float* at = a_trg + h * F;
  float d1 = 0.f, d2 = 0.f;
#pragma unroll
  for (int f = 0; f < F; f += 8) {
    float4 raw = *reinterpret_cast<const float4*>(p + f);  // 8 halves
    const __half2* hp = reinterpret_cast<const __half2*>(&raw);
    float2 p01 = __half22float2(hp[0]);
    float2 p23 = __half22float2(hp[1]);
    float2 p45 = __half22float2(hp[2]);
    float2 p67 = __half22float2(hp[3]);
    float4 a0 = *reinterpret_cast<const float4*>(as + f);
    float4 a1 = *reinterpret_cast<const float4*>(as + f + 4);
    float4 t0 = *reinterpret_cast<const float4*>(at + f);
    float4 t1 = *reinterpret_cast<const float4*>(at + f + 4);
    d1 += p01.x * a0.x + p01.y * a0.y + p23.x * a0.z + p23.y * a0.w +
          p45.x * a1.x + p45.y * a1.y + p67.x * a1.z + p67.y * a1.w;
    d2 += p01.x * t0.x + p01.y * t0.y + p23.x * t0.z + p23.y * t0.w +
          p45.x * t1.x + p45.y * t1.y + p67.x * t1.z + p67.y * t1.w;
  }
  ssrc[idx] = d1;
  strg[idx] = d2;
}

// ---------------------------------------------------------------------------
// Fused aggregation: fp16 gather + fp16 skip; out fp16 (layer1) or fp32.
// ---------------------------------------------------------------------------
template <int H, int F, bool OUT_F16>
__global__ void aggregate(const int2* __restrict__ edge2, const int* __restrict__ row_off,
                          const float* __restrict__ ssrc, const float* __restrict__ strg,
                          const float* __restrict__ Wt, const float* __restrict__ a_tp,
                          const __half* __restrict__ projh, const __half* __restrict__ skiph,
                          const float* __restrict__ bias, void* __restrict__ outv, int N) {
  static_assert(H * F == 128, "offset shift assumes H*F==128");
  int wid = (blockIdx.x * blockDim.x + threadIdx.x) >> 6;
  if (wid >= N) return;
  const int lane = threadIdx.x & 63;
  const int half = lane >> 5;
  const int fl = (lane & 31) * 4;
  const int h = fl / F;

  float4 wt4 = *reinterpret_cast<const float4*>(Wt + fl);
  float4 at4 = *reinterpret_cast<const float4*>(a_tp + fl);
  float ch = wt4.x * at4.x + wt4.y * at4.y + wt4.z * at4.z + wt4.w * at4.w;
#pragma unroll
  for (int off = 1; off < (F / 4); off <<= 1) ch += __shfl_xor(ch, off);

  const float mt = strg[wid * H + h];
  const int beg = row_off[wid];
  const int end = row_off[wid + 1];

  float ax = 0.f, ay = 0.f, az = 0.f, aw = 0.f;
  float denom = 0.f;

  for (int i = beg; i < end; i += 8) {
    int   s[4];
    float pe[4], vd[4];
    float2 raw[4];
#pragma unroll
    for (int q = 0; q < 4; ++q) {
      int ii = i + q * 2 + half;
      bool v = ii < end;
      int2 e2 = v ? edge2[ii] : make_int2(0, 0);
      s[q] = e2.x;
      pe[q] = __int_as_float(e2.y);
      vd[q] = v ? 1.f : 0.f;
    }
#pragma unroll
    for (int q = 0; q < 4; ++q)
      raw[q] = *reinterpret_cast<const float2*>(projh + (s[q] << 7) + fl);
#pragma unroll
    for (int q = 0; q < 4; ++q) {
      float sc = ssrc[s[q] * H + h] + mt + pe[q] * ch;
      sc = sc > 0.f ? sc : 0.2f * sc;
      float ee = __expf(sc) * vd[q];
      __half2 h01 = *reinterpret_cast<__half2*>(&raw[q].x);
      __half2 h23 = *reinterpret_cast<__half2*>(&raw[q].y);
      float2 f01 = __half22float2(h01);
      float2 f23 = __half22float2(h23);
      denom += ee;
      ax += f01.x * ee;
      ay += f01.y * ee;
      az += f23.x * ee;
      aw += f23.y * ee;
    }
  }

  denom += __shfl_xor(denom, 32);
  ax += __shfl_xor(ax, 32);
  ay += __shfl_xor(ay, 32);
  az += __shfl_xor(az, 32);
  aw += __shfl_xor(aw, 32);

  if (half == 0) {
    float inv = 1.0f / (denom + 1e-16f);
    int base = (wid << 7) + fl;
    float2 skraw = *reinterpret_cast<const float2*>(skiph + base);  // 4 halves
    const __half2* sp = reinterpret_cast<const __half2*>(&skraw);
    float2 s01 = __half22float2(sp[0]);
    float2 s23 = __half22float2(sp[1]);
    float4 bi = *reinterpret_cast<const float4*>(bias + fl);
    float o0 = ax * inv + s01.x + bi.x;
    float o1 = ay * inv + s01.y + bi.y;
    float o2 = az * inv + s23.x + bi.z;
    float o3 = aw * inv + s23.y + bi.w;
    o0 = o0 > 0.f ? o0 : __expf(o0) - 1.f;
    o1 = o1 > 0.f ? o1 : __expf(o1) - 1.f;
    o2 = o2 > 0.f ? o2 : __expf(o2) - 1.f;
    o3 = o3 > 0.f ? o3 : __expf(o3) - 1.f;
    if (OUT_F16) {
      __half2 w01 = __floats2half2_rn(o0, o1);
      __half2 w23 = __floats2half2_rn(o2, o3);
      float2 wv;
      reinterpret_cast<__half2*>(&wv)[0] = w01;
      reinterpret_cast<__half2*>(&wv)[1] = w23;
      *reinterpret_cast<float2*>(reinterpret_cast<__half*>(outv) + base) = wv;
    } else {
      *reinterpret_cast<float4*>(reinterpret_cast<float*>(outv) + base) =
          make_float4(o0, o1, o2, o3);
    }
  }
}

// ---------------------------------------------------------------------------
extern "C" void kernel_launch(void* const* d_in, const int* in_sizes, int n_in,
                              void* d_out, int out_size, void* d_ws, size_t ws_size,
                              hipStream_t stream) {
  const float* x      = (const float*)d_in[0];
  const int*   ei     = (const int*)  d_in[1];
  const float* ep     = (const float*)d_in[2];
  const float* W1     = (const float*)d_in[3];
  const float* Wt1    = (const float*)d_in[4];
  const float* a_src1 = (const float*)d_in[5];
  const float* a_trg1 = (const float*)d_in[6];
  const float* a_tp1  = (const float*)d_in[7];
  const float* b1     = (const float*)d_in[8];
  const float* Wskip1 = (const float*)d_in[9];
  const float* W2     = (const float*)d_in[10];
  const float* Wt2    = (const float*)d_in[11];
  const float* a_src2 = (const float*)d_in[12];
  const float* a_trg2 = (const float*)d_in[13];
  const float* a_tp2  = (const float*)d_in[14];
  const float* b2     = (const float*)d_in[15];

  const int N = in_sizes[0] / 128;
  const int E = in_sizes[1] / 2;
  const int* srcA = ei;
  const int* trgA = ei + E;

  char* ws = (char*)d_ws;
  size_t off = 0;
  auto alloc = [&](size_t bytes) {
    void* p = ws + off;
    off += (bytes + 255) & ~(size_t)255;
    return p;
  };
  int*    bhist   = (int*)   alloc((size_t)256 * 4);
  int*    bcur    = (int*)   alloc((size_t)256 * 4);
  int*    boffx   = (int*)   alloc((size_t)257 * 4);
  int*    row_off = (int*)   alloc((size_t)(N + 1) * 4);
  int2*   staging = (int2*)  alloc((size_t)E * 8);
  int2*   edge2   = (int2*)  alloc((size_t)E * 8);
  __half* xh      = (__half*)alloc((size_t)N * 128 * 2);
  __half* projh   = (__half*)alloc((size_t)N * 128 * 2);
  __half* skiph   = (__half*)alloc((size_t)N * 128 * 2);
  __half* hbufh   = (__half*)alloc((size_t)N * 128 * 2);
  __half* Bp1     = (__half*)alloc((size_t)2048 * 8 * 2);
  __half* BpS     = (__half*)alloc((size_t)2048 * 8 * 2);
  __half* Bp2     = (__half*)alloc((size_t)2048 * 8 * 2);
  float*  ssrc    = (float*) alloc((size_t)N * 8 * 4);
  float*  strg    = (float*) alloc((size_t)N * 8 * 4);
  (void)ws_size; (void)n_in; (void)out_size;

  hipMemsetAsync(bhist, 0, 256 * 4, stream);

  const int eb4 = (E + 1023) / 1024;
  const int gb = (N + 63) / 64;
  const int nb = (N + 255) / 256;

  // Input conversion + weight packing (independent of CSR build)
  f32_to_f16<<<(N * 16 + 255) / 256, 256, 0, stream>>>(x, xh, N * 16);  // N*128/8
  pack_b<<<8, 256, 0, stream>>>(W1, Bp1);
  pack_b<<<8, 256, 0, stream>>>(Wskip1, BpS);
  pack_b<<<8, 256, 0, stream>>>(W2, Bp2);

  // CSR build (shared by both layers)
  bucket_hist<<<eb4, 256, 0, stream>>>(trgA, bhist, E);
  scan196<<<1, 256, 0, stream>>>(bhist, boffx, bcur, row_off, nb, N);
  bucket_scatter<<<eb4, 256, 0, stream>>>(srcA, trgA, ep, boffx, bcur, staging, E, N);
  bucket_place<<<nb, 256, 0, stream>>>(staging, boffx, row_off, edge2, N);

  // -------- Layer 1: H=8, F=16, concat, skip = x @ Wskip1 --------
  gemm_mfma_dual<<<gb, 256, 0, stream>>>(xh, (const half8*)Bp1, (const half8*)BpS,
                                         projh, skiph, N);
  node_scores_h<8, 16><<<(N * 8 + 255) / 256, 256, 0, stream>>>(projh, a_src1, a_trg1,
                                                                ssrc, strg, N);
  aggregate<8, 16, true><<<(N + 3) / 4, 256, 0, stream>>>(edge2, row_off, ssrc, strg, Wt1,
                                                          a_tp1, projh, skiph, b1, hbufh, N);

  // -------- Layer 2: H=1, F=128, mean (=identity), skip = identity --------
  gemm_mfma<<<gb, 256, 0, stream>>>(hbufh, (const half8*)Bp2, projh, N);
  node_scores_h<1, 128><<<(N + 255) / 256, 256, 0, stream>>>(projh, a_src2, a_trg2,
                                                             ssrc, strg, N);
  aggregate<1, 128, false><<<(N + 3) / 4, 256, 0, stream>>>(edge2, row_off, ssrc, strg, Wt2,
                                                            a_tp2, projh, hbufh, b2,
                                                            (float*)d_out, N);
}

// Round 13
// 342.105 us; speedup vs baseline: 1.7203x; 1.0078x over previous
//
#include <hip/hip_runtime.h>
#include <hip/hip_fp16.h>
#include <cstdint>
#include <cstddef>

typedef _Float16 half8 __attribute__((ext_vector_type(8)));
typedef float f32x4 __attribute__((ext_vector_type(4)));

// ---------------------------------------------------------------------------
// Pack three 128x128 fp32 B matrices into MFMA-fragment-ordered fp16.
// slot=(kt*8+nt)*64+lane; elem j = B[kt*32+(lane>>4)*8+j][nt*16+(lane&15)]
// ---------------------------------------------------------------------------
__global__ void pack_b3(const float* __restrict__ B1, const float* __restrict__ BS,
                        const float* __restrict__ B2, __half* __restrict__ Bp1,
                        __half* __restrict__ BpS, __half* __restrict__ Bp2) {
  int g = blockIdx.x >> 3;
  const float* B = (g == 0) ? B1 : (g == 1) ? BS : B2;
  __half* Bp = (g == 0) ? Bp1 : (g == 1) ? BpS : Bp2;
  int slot = (blockIdx.x & 7) * 256 + threadIdx.x;
  int lane = slot & 63;
  int nt = (slot >> 6) & 7;
  int kt = slot >> 9;
  int r0 = kt * 32 + (lane >> 4) * 8;
  int col = nt * 16 + (lane & 15);
  __half tmp[8];
#pragma unroll
  for (int j = 0; j < 8; ++j) tmp[j] = __float2half(B[(r0 + j) * 128 + col]);
  *reinterpret_cast<float4*>(Bp + (size_t)slot * 8) = *reinterpret_cast<float4*>(tmp);
}

__global__ void f32_to_f16(const float* __restrict__ in, __half* __restrict__ out, int n8) {
  int i = blockIdx.x * 256 + threadIdx.x;
  if (i >= n8) return;
  float4 a = *reinterpret_cast<const float4*>(in + (size_t)i * 8);
  float4 b = *reinterpret_cast<const float4*>(in + (size_t)i * 8 + 4);
  __half2 h[4] = {__floats2half2_rn(a.x, a.y), __floats2half2_rn(a.z, a.w),
                  __floats2half2_rn(b.x, b.y), __floats2half2_rn(b.z, b.w)};
  *reinterpret_cast<float4*>(out + (size_t)i * 8) = *reinterpret_cast<float4*>(h);
}

// ---------------------------------------------------------------------------
// Layer-1 GEMM: proj = A@W1, skip = A@Wskip (fp16 out) + FUSED node scores
// (H=8,F=16: head h == col-tile nt). No LDS.
// ---------------------------------------------------------------------------
__global__ __launch_bounds__(256) void gemm_mfma_dual(
    const __half* __restrict__ Ah, const half8* __restrict__ Bp1,
    const half8* __restrict__ Bp2, const float* __restrict__ a_src,
    const float* __restrict__ a_trg, __half* __restrict__ C1, __half* __restrict__ C2,
    float* __restrict__ ssrc, float* __restrict__ strg, int M) {
  const int w = threadIdx.x >> 6, lane = threadIdx.x & 63;
  const int row0 = blockIdx.x * 64 + w * 16;
  const int arow = row0 + (lane & 15);
  const int kb = (lane >> 4) * 8;
  const bool av = arow < M;
  f32x4 acc1[8] = {};
  f32x4 acc2[8] = {};
  for (int kt = 0; kt < 4; ++kt) {
    half8 af = {};
    if (av) af = *reinterpret_cast<const half8*>(Ah + (size_t)arow * 128 + kt * 32 + kb);
    const half8* b1 = Bp1 + (kt * 8) * 64 + lane;
    const half8* b2 = Bp2 + (kt * 8) * 64 + lane;
#pragma unroll
    for (int nt = 0; nt < 8; ++nt) {
      acc1[nt] = __builtin_amdgcn_mfma_f32_16x16x32_f16(af, b1[nt * 64], acc1[nt], 0, 0, 0);
      acc2[nt] = __builtin_amdgcn_mfma_f32_16x16x32_f16(af, b2[nt * 64], acc2[nt], 0, 0, 0);
    }
  }
  const int orow = row0 + (lane >> 4) * 4;
  const int col = lane & 15;
  float asv[8], atv[8];
#pragma unroll
  for (int h2 = 0; h2 < 8; ++h2) {
    asv[h2] = a_src[h2 * 16 + col];
    atv[h2] = a_trg[h2 * 16 + col];
  }
#pragma unroll
  for (int r = 0; r < 4; ++r) {
    int rr = orow + r;
    if (rr >= M) continue;
#pragma unroll
    for (int nt = 0; nt < 8; ++nt) {
      C1[(size_t)rr * 128 + nt * 16 + col] = __float2half(acc1[nt][r]);
      C2[(size_t)rr * 128 + nt * 16 + col] = __float2half(acc2[nt][r]);
    }
    float sv[8], tv[8];
#pragma unroll
    for (int h2 = 0; h2 < 8; ++h2) {
      sv[h2] = acc1[h2][r] * asv[h2];
      tv[h2] = acc1[h2][r] * atv[h2];
    }
#pragma unroll
    for (int off = 1; off < 16; off <<= 1) {
#pragma unroll
      for (int h2 = 0; h2 < 8; ++h2) {
        sv[h2] += __shfl_xor(sv[h2], off);
        tv[h2] += __shfl_xor(tv[h2], off);
      }
    }
    if (col == 0) {
      *reinterpret_cast<float4*>(ssrc + rr * 8) = make_float4(sv[0], sv[1], sv[2], sv[3]);
      *reinterpret_cast<float4*>(ssrc + rr * 8 + 4) = make_float4(sv[4], sv[5], sv[6], sv[7]);
      *reinterpret_cast<float4*>(strg + rr * 8) = make_float4(tv[0], tv[1], tv[2], tv[3]);
      *reinterpret_cast<float4*>(strg + rr * 8 + 4) = make_float4(tv[4], tv[5], tv[6], tv[7]);
    }
  }
}

// ---------------------------------------------------------------------------
// Layer-2 GEMM: proj = A@W2 (fp16 out) + FUSED node scores (H=1,F=128).
// ---------------------------------------------------------------------------
__global__ __launch_bounds__(256) void gemm_mfma_s(
    const __half* __restrict__ Ah, const half8* __restrict__ Bp,
    const float* __restrict__ a_src, const float* __restrict__ a_trg,
    __half* __restrict__ C, float* __restrict__ ssrc, float* __restrict__ strg, int M) {
  const int w = threadIdx.x >> 6, lane = threadIdx.x & 63;
  const int row0 = blockIdx.x * 64 + w * 16;
  const int arow = row0 + (lane & 15);
  const int kb = (lane >> 4) * 8;
  const bool av = arow < M;
  f32x4 acc[8] = {};
  for (int kt = 0; kt < 4; ++kt) {
    half8 af = {};
    if (av) af = *reinterpret_cast<const half8*>(Ah + (size_t)arow * 128 + kt * 32 + kb);
    const half8* bb = Bp + (kt * 8) * 64 + lane;
#pragma unroll
    for (int nt = 0; nt < 8; ++nt)
      acc[nt] = __builtin_amdgcn_mfma_f32_16x16x32_f16(af, bb[nt * 64], acc[nt], 0, 0, 0);
  }
  const int orow = row0 + (lane >> 4) * 4;
  const int col = lane & 15;
  float asv[8], atv[8];
#pragma unroll
  for (int nt = 0; nt < 8; ++nt) {
    asv[nt] = a_src[nt * 16 + col];
    atv[nt] = a_trg[nt * 16 + col];
  }
#pragma unroll
  for (int r = 0; r < 4; ++r) {
    int rr = orow + r;
    if (rr >= M) continue;
    float sp = 0.f, tp = 0.f;
#pragma unroll
    for (int nt = 0; nt < 8; ++nt) {
      C[(size_t)rr * 128 + nt * 16 + col] = __float2half(acc[nt][r]);
      sp += acc[nt][r] * asv[nt];
      tp += acc[nt][r] * atv[nt];
    }
#pragma unroll
    for (int off = 1; off < 16; off <<= 1) {
      sp += __shfl_xor(sp, off);
      tp += __shfl_xor(tp, off);
    }
    if (col == 0) {
      ssrc[rr] = sp;
      strg[rr] = tp;
    }
  }
}

// ---------------------------------------------------------------------------
// CSR build v3 (unchanged, verified passing)
// ---------------------------------------------------------------------------
__global__ __launch_bounds__(256) void bucket_hist(const int* __restrict__ trg,
                                                   int* __restrict__ bhist, int E) {
  __shared__ int cnt[256];
  cnt[threadIdx.x] = 0;
  __syncthreads();
  const int base = blockIdx.x * 1024;
#pragma unroll
  for (int j = 0; j < 4; ++j) {
    int e = base + threadIdx.x + j * 256;
    if (e < E) atomicAdd(&cnt[trg[e] >> 8], 1);
  }
  __syncthreads();
  int c = cnt[threadIdx.x];
  if (c) atomicAdd(&bhist[threadIdx.x], c);
}

__global__ void scan196(const int* __restrict__ bhist, int* __restrict__ boffx,
                        int* __restrict__ bcur, int* __restrict__ row_off, int nb, int N) {
  __shared__ int s[256];
  int t = threadIdx.x;
  bcur[t] = 0;
  int v = (t < nb) ? bhist[t] : 0;
  s[t] = v;
  __syncthreads();
#pragma unroll
  for (int off = 1; off < 256; off <<= 1) {
    int x = s[t];
    int add = (t >= off) ? s[t - off] : 0;
    __syncthreads();
    s[t] = x + add;
    __syncthreads();
  }
  if (t < nb) boffx[t] = (t == 0) ? 0 : s[t - 1];
  if (t == 0) {
    boffx[nb] = s[255];
    row_off[N] = s[255];
  }
}

__global__ __launch_bounds__(256) void bucket_scatter(
    const int* __restrict__ src, const int* __restrict__ trg,
    const float* __restrict__ ep, const int* __restrict__ boffx,
    int* __restrict__ bcur, int2* __restrict__ staging, int E, int N) {
  __shared__ int cnt[256], boff[256], rowb[256];
  const int nb2 = (N + 255) >> 8;
  if (threadIdx.x < nb2) cnt[threadIdx.x] = 0;
  __syncthreads();
  const int base = blockIdx.x * 1024;
  int b_[4], r_[4], s_[4], p_[4];
#pragma unroll
  for (int j = 0; j < 4; ++j) {
    int e = base + threadIdx.x + j * 256;
    bool v = e < E;
    int tg = v ? trg[e] : 0;
    int sc = v ? src[e] : 0;
    p_[j] = v ? __float_as_int(ep[e]) : 0;
    b_[j] = tg >> 8;
    s_[j] = sc | ((tg & 255) << 16);
    r_[j] = v ? atomicAdd(&cnt[b_[j]], 1) : -1;
  }
  __syncthreads();
  if (threadIdx.x < nb2) {
    int c = cnt[threadIdx.x];
    boff[threadIdx.x] = c ? atomicAdd(&bcur[threadIdx.x], c) : 0;
    rowb[threadIdx.x] = boffx[threadIdx.x];
  }
  __syncthreads();
#pragma unroll
  for (int j = 0; j < 4; ++j) {
    if (r_[j] >= 0) {
      int b = b_[j];
      staging[rowb[b] + boff[b] + r_[j]] = make_int2(s_[j], p_[j]);
    }
  }
}

__global__ __launch_bounds__(256) void bucket_place(
    const int2* __restrict__ staging, const int* __restrict__ boffx,
    int* __restrict__ row_off, int2* __restrict__ edge2, int N) {
  __shared__ int cnt[256], loc[256], cur[256];
  const int t = threadIdx.x;
  const int n0 = blockIdx.x << 8;
  const int nn = min(256, N - n0);
  cnt[t] = 0;
  __syncthreads();
  const int lo = boffx[blockIdx.x];
  const int hi = boffx[blockIdx.x + 1];
  for (int i = lo + t; i < hi; i += 256) {
    atomicAdd(&cnt[(staging[i].x >> 16) & 255], 1);
  }
  __syncthreads();
  loc[t] = cnt[t];
  __syncthreads();
#pragma unroll
  for (int off = 1; off < 256; off <<= 1) {
    int x = loc[t];
    int add = (t >= off) ? loc[t - off] : 0;
    __syncthreads();
    loc[t] = x + add;
    __syncthreads();
  }
  int excl = loc[t] - cnt[t];
  if (t < nn) row_off[n0 + t] = lo + excl;
  cur[t] = lo + excl;
  __syncthreads();
  for (int i = lo + t; i < hi; i += 256) {
    int2 v = staging[i];
    int ln = (v.x >> 16) & 255;
    int pos = atomicAdd(&cur[ln], 1);
    edge2[pos] = make_int2(v.x & 0xFFFF, v.y);
  }
}

// ---------------------------------------------------------------------------
// Fused aggregation: 16 edges/iter (8 per half) for deeper MLP.
// ---------------------------------------------------------------------------
template <int H, int F, bool OUT_F16>
__global__ void aggregate(const int2* __restrict__ edge2, const int* __restrict__ row_off,
                          const float* __restrict__ ssrc, const float* __restrict__ strg,
                          const float* __restrict__ Wt, const float* __restrict__ a_tp,
                          const __half* __restrict__ projh, const __half* __restrict__ skiph,
                          const float* __restrict__ bias, void* __restrict__ outv, int N) {
  static_assert(H * F == 128, "offset shift assumes H*F==128");
  int wid = (blockIdx.x * blockDim.x + threadIdx.x) >> 6;
  if (wid >= N) return;
  const int lane = threadIdx.x & 63;
  const int half = lane >> 5;
  const int fl = (lane & 31) * 4;
  const int h = fl / F;

  float4 wt4 = *reinterpret_cast<const float4*>(Wt + fl);
  float4 at4 = *reinterpret_cast<const float4*>(a_tp + fl);
  float ch = wt4.x * at4.x + wt4.y * at4.y + wt4.z * at4.z + wt4.w * at4.w;
#pragma unroll
  for (int off = 1; off < (F / 4); off <<= 1) ch += __shfl_xor(ch, off);

  const float mt = strg[wid * H + h];
  const int beg = row_off[wid];
  const int end = row_off[wid + 1];

  float ax = 0.f, ay = 0.f, az = 0.f, aw = 0.f;
  float denom = 0.f;

  for (int i = beg; i < end; i += 16) {
    int   s[8];
    float pe[8], vd[8];
    float2 raw[8];
#pragma unroll
    for (int q = 0; q < 8; ++q) {
      int ii = i + q * 2 + half;
      bool v = ii < end;
      int2 e2 = v ? edge2[ii] : make_int2(0, 0);
      s[q] = e2.x;
      pe[q] = __int_as_float(e2.y);
      vd[q] = v ? 1.f : 0.f;
    }
#pragma unroll
    for (int q = 0; q < 8; ++q)
      raw[q] = *reinterpret_cast<const float2*>(projh + (s[q] << 7) + fl);
#pragma unroll
    for (int q = 0; q < 8; ++q) {
      float sc = ssrc[s[q] * H + h] + mt + pe[q] * ch;
      sc = sc > 0.f ? sc : 0.2f * sc;
      float ee = __expf(sc) * vd[q];
      __half2 h01 = *reinterpret_cast<__half2*>(&raw[q].x);
      __half2 h23 = *reinterpret_cast<__half2*>(&raw[q].y);
      float2 f01 = __half22float2(h01);
      float2 f23 = __half22float2(h23);
      denom += ee;
      ax += f01.x * ee;
      ay += f01.y * ee;
      az += f23.x * ee;
      aw += f23.y * ee;
    }
  }

  denom += __shfl_xor(denom, 32);
  ax += __shfl_xor(ax, 32);
  ay += __shfl_xor(ay, 32);
  az += __shfl_xor(az, 32);
  aw += __shfl_xor(aw, 32);

  if (half == 0) {
    float inv = 1.0f / (denom + 1e-16f);
    int base = (wid << 7) + fl;
    float2 skraw = *reinterpret_cast<const float2*>(skiph + base);
    const __half2* sp = reinterpret_cast<const __half2*>(&skraw);
    float2 s01 = __half22float2(sp[0]);
    float2 s23 = __half22float2(sp[1]);
    float4 bi = *reinterpret_cast<const float4*>(bias + fl);
    float o0 = ax * inv + s01.x + bi.x;
    float o1 = ay * inv + s01.y + bi.y;
    float o2 = az * inv + s23.x + bi.z;
    float o3 = aw * inv + s23.y + bi.w;
    o0 = o0 > 0.f ? o0 : __expf(o0) - 1.f;
    o1 = o1 > 0.f ? o1 : __expf(o1) - 1.f;
    o2 = o2 > 0.f ? o2 : __expf(o2) - 1.f;
    o3 = o3 > 0.f ? o3 : __expf(o3) - 1.f;
    if (OUT_F16) {
      __half2 w01 = __floats2half2_rn(o0, o1);
      __half2 w23 = __floats2half2_rn(o2, o3);
      float2 wv;
      reinterpret_cast<__half2*>(&wv)[0] = w01;
      reinterpret_cast<__half2*>(&wv)[1] = w23;
      *reinterpret_cast<float2*>(reinterpret_cast<__half*>(outv) + base) = wv;
    } else {
      *reinterpret_cast<float4*>(reinterpret_cast<float*>(outv) + base) =
          make_float4(o0, o1, o2, o3);
    }
  }
}

// ---------------------------------------------------------------------------
extern "C" void kernel_launch(void* const* d_in, const int* in_sizes, int n_in,
                              void* d_out, int out_size, void* d_ws, size_t ws_size,
                              hipStream_t stream) {
  const float* x      = (const float*)d_in[0];
  const int*   ei     = (const int*)  d_in[1];
  const float* ep     = (const float*)d_in[2];
  const float* W1     = (const float*)d_in[3];
  const float* Wt1    = (const float*)d_in[4];
  const float* a_src1 = (const float*)d_in[5];
  const float* a_trg1 = (const float*)d_in[6];
  const float* a_tp1  = (const float*)d_in[7];
  const float* b1     = (const float*)d_in[8];
  const float* Wskip1 = (const float*)d_in[9];
  const float* W2     = (const float*)d_in[10];
  const float* Wt2    = (const float*)d_in[11];
  const float* a_src2 = (const float*)d_in[12];
  const float* a_trg2 = (const float*)d_in[13];
  const float* a_tp2  = (const float*)d_in[14];
  const float* b2     = (const float*)d_in[15];

  const int N = in_sizes[0] / 128;
  const int E = in_sizes[1] / 2;
  const int* srcA = ei;
  const int* trgA = ei + E;

  char* ws = (char*)d_ws;
  size_t off = 0;
  auto alloc = [&](size_t bytes) {
    void* p = ws + off;
    off += (bytes + 255) & ~(size_t)255;
    return p;
  };
  int*    bhist   = (int*)   alloc((size_t)256 * 4);
  int*    bcur    = (int*)   alloc((size_t)256 * 4);
  int*    boffx   = (int*)   alloc((size_t)257 * 4);
  int*    row_off = (int*)   alloc((size_t)(N + 1) * 4);
  int2*   staging = (int2*)  alloc((size_t)E * 8);
  int2*   edge2   = (int2*)  alloc((size_t)E * 8);
  __half* xh      = (__half*)alloc((size_t)N * 128 * 2);
  __half* projh   = (__half*)alloc((size_t)N * 128 * 2);
  __half* skiph   = (__half*)alloc((size_t)N * 128 * 2);
  __half* hbufh   = (__half*)alloc((size_t)N * 128 * 2);
  __half* Bp1     = (__half*)alloc((size_t)2048 * 8 * 2);
  __half* BpS     = (__half*)alloc((size_t)2048 * 8 * 2);
  __half* Bp2     = (__half*)alloc((size_t)2048 * 8 * 2);
  float*  ssrc    = (float*) alloc((size_t)N * 8 * 4);
  float*  strg    = (float*) alloc((size_t)N * 8 * 4);
  (void)ws_size; (void)n_in; (void)out_size;

  hipMemsetAsync(bhist, 0, 256 * 4, stream);

  const int eb4 = (E + 1023) / 1024;
  const int gb = (N + 63) / 64;
  const int nb = (N + 255) / 256;

  f32_to_f16<<<(N * 16 + 255) / 256, 256, 0, stream>>>(x, xh, N * 16);
  pack_b3<<<24, 256, 0, stream>>>(W1, Wskip1, W2, Bp1, BpS, Bp2);

  // CSR build (shared by both layers)
  bucket_hist<<<eb4, 256, 0, stream>>>(trgA, bhist, E);
  scan196<<<1, 256, 0, stream>>>(bhist, boffx, bcur, row_off, nb, N);
  bucket_scatter<<<eb4, 256, 0, stream>>>(srcA, trgA, ep, boffx, bcur, staging, E, N);
  bucket_place<<<nb, 256, 0, stream>>>(staging, boffx, row_off, edge2, N);

  // -------- Layer 1: H=8, F=16, concat, skip = x @ Wskip1 --------
  gemm_mfma_dual<<<gb, 256, 0, stream>>>(xh, (const half8*)Bp1, (const half8*)BpS,
                                         a_src1, a_trg1, projh, skiph, ssrc, strg, N);
  aggregate<8, 16, true><<<(N + 3) / 4, 256, 0, stream>>>(edge2, row_off, ssrc, strg, Wt1,
                                                          a_tp1, projh, skiph, b1, hbufh, N);

  // -------- Layer 2: H=1, F=128, mean (=identity), skip = identity --------
  gemm_mfma_s<<<gb, 256, 0, stream>>>(hbufh, (const half8*)Bp2, a_src2, a_trg2,
                                      projh, ssrc, strg, N);
  aggregate<1, 128, false><<<(N + 3) / 4, 256, 0, stream>>>(edge2, row_off, ssrc, strg, Wt2,
                                                            a_tp2, projh, hbufh, b2,
                                                            (float*)d_out, N);
}